// Round 2
// baseline (259.723 us; speedup 1.0000x reference)
//
#include <hip/hip_runtime.h>
#include <hip/hip_bf16.h>

typedef unsigned short u16;
typedef __bf16 v8bf __attribute__((ext_vector_type(8)));
typedef float f32x4 __attribute__((ext_vector_type(4)));
typedef unsigned int u32x4 __attribute__((ext_vector_type(4)));

constexpr int BATCH = 2048;
constexpr int DIM   = 512;
constexpr int NCLS  = 10000;
constexpr int NPAD  = 10112;   // 79 * 128

#define F_S     30.0f
#define F_COS_M 0.9800665778412416f
#define F_SIN_M 0.19866933079506122f
#define F_TH   (-0.9800665778412416f)
#define F_MM    0.03973386615901224f

static __device__ __forceinline__ float clampf(float v, float lo, float hi) {
    return fminf(fmaxf(v, lo), hi);
}
static __device__ __forceinline__ u16 f2bf(float v) {
    __hip_bfloat16 h = __float2bfloat16(v);
    return __builtin_bit_cast(unsigned short, h);
}
// async global->LDS, 16B per lane. LDS dest must be wave-uniform-base + lane*16.
static __device__ __forceinline__ void glds16(const void* g, void* l) {
    __builtin_amdgcn_global_load_lds(
        (const __attribute__((address_space(1))) unsigned int*)g,
        (__attribute__((address_space(3))) unsigned int*)l, 16, 0, 0);
}
static __device__ __forceinline__ float blk_sum(float v, float* sh, int t) {
#pragma unroll
    for (int o = 32; o > 0; o >>= 1) v += __shfl_down(v, o, 64);
    __syncthreads();
    if ((t & 63) == 0) sh[t >> 6] = v;
    __syncthreads();
    return sh[0] + sh[1] + sh[2] + sh[3];
}

// ============ merged normalize (x rows | w rows | gathered wm/wn rows) + acc zeroing ============
__global__ __launch_bounds__(256) void norm_all_kernel(const float* __restrict__ x,
                                                       const float* __restrict__ w,
                                                       const float* __restrict__ wm,
                                                       const float* __restrict__ wn,
                                                       const int* __restrict__ label,
                                                       u16* __restrict__ xnb,
                                                       u16* __restrict__ wb,
                                                       u16* __restrict__ wqb,
                                                       u16* __restrict__ wkb,
                                                       float* __restrict__ zacc) {
    __shared__ float sh[8];
    const int b = blockIdx.x, t = threadIdx.x;
    if (b < 33) zacc[b * 256 + t] = 0.f;   // zero accumulators/tickets (8448 >= 8196 used)

    if (b < BATCH) {
        const float* p = x + (size_t)b * DIM;
        float x0 = p[t], x1 = p[t + 256];
        float s = blk_sum(x0 * x0 + x1 * x1, sh, t);
        float inv = 1.0f / fmaxf(sqrtf(s), 1e-12f);
        xnb[(size_t)b * DIM + t]       = f2bf(x0 * inv);
        xnb[(size_t)b * DIM + t + 256] = f2bf(x1 * inv);
    } else if (b < BATCH + NPAD) {
        const int row = b - BATCH;
        if (row >= NCLS) {
            wb[(size_t)row * DIM + t] = 0;
            wb[(size_t)row * DIM + t + 256] = 0;
            return;
        }
        const float* p = w + (size_t)row * DIM;
        float x0 = p[t], x1 = p[t + 256];
        float s = blk_sum(x0 * x0 + x1 * x1, sh, t);
        float inv = 1.0f / fmaxf(sqrtf(s), 1e-12f);
        wb[(size_t)row * DIM + t]       = f2bf(x0 * inv);
        wb[(size_t)row * DIM + t + 256] = f2bf(x1 * inv);
    } else {
        const int i = b - (BATCH + NPAD);
        const int g = label[i];
        const float* pq = wm + (size_t)g * DIM;
        const float* pk = wn + (size_t)g * DIM;
        float q0 = pq[t], q1 = pq[t + 256];
        float k0 = pk[t], k1 = pk[t + 256];
        float sq = blk_sum(q0 * q0 + q1 * q1, sh, t);
        float sk = blk_sum(k0 * k0 + k1 * k1, sh + 4, t);
        float iq = 1.0f / fmaxf(sqrtf(sq), 1e-12f);
        float ik = 1.0f / fmaxf(sqrtf(sk), 1e-12f);
        wqb[(size_t)i * DIM + t]       = f2bf(q0 * iq);
        wqb[(size_t)i * DIM + t + 256] = f2bf(q1 * iq);
        wkb[(size_t)i * DIM + t]       = f2bf(k0 * ik);
        wkb[(size_t)i * DIM + t + 256] = f2bf(k1 * ik);
    }
}

// ============ AAM GEMM (128x128 tile, BK=64, global_load_lds staging) + fused softmax sums ============
__global__ __launch_bounds__(256) void gemm_aam_kernel(const u16* __restrict__ A,
                                                       const u16* __restrict__ B,
                                                       const int* __restrict__ label,
                                                       float* __restrict__ sumexp,
                                                       float* __restrict__ sumlogit,
                                                       float* __restrict__ philab) {
    __shared__ __align__(16) u16 As[128 * 64];   // 16 KB, unpadded (glds requirement)
    __shared__ __align__(16) u16 Bs[128 * 64];
    __shared__ float red_e[128];
    __shared__ float red_l[128];

    const int t = threadIdx.x;
    const int lane = t & 63, wave = t >> 6;
    const int wm = (wave >> 1) * 64, wn = (wave & 1) * 64;
    const int fr = lane & 15, quad = lane >> 4;
    const int bm = blockIdx.x, bn = blockIdx.y;

    if (t < 128) { red_e[t] = 0.f; red_l[t] = 0.f; }

    const int srow = t >> 3;        // 0..31, +r*32
    const int sch  = t & 7;         // 16B chunk within 128B row-slice
    const u16* ag = A + (size_t)(bm * 128 + srow) * DIM + sch * 8;
    const u16* bg = B + (size_t)(bn * 128 + srow) * DIM + sch * 8;
    u16* al = &As[srow * 64 + sch * 8];
    u16* bl = &Bs[srow * 64 + sch * 8];

    f32x4 acc[4][4] = {};

    for (int k0 = 0; k0 < DIM; k0 += 64) {
#pragma unroll
        for (int r = 0; r < 4; r++) {
            glds16(ag + (size_t)(r * 32) * DIM + k0, al + r * 32 * 64);
            glds16(bg + (size_t)(r * 32) * DIM + k0, bl + r * 32 * 64);
        }
        __syncthreads();
#pragma unroll
        for (int ks = 0; ks < 2; ks++) {
            v8bf af[4], bf[4];
#pragma unroll
            for (int f = 0; f < 4; f++) {
                af[f] = __builtin_bit_cast(v8bf, *(const u32x4*)&As[(wm + f * 16 + fr) * 64 + ks * 32 + quad * 8]);
                bf[f] = __builtin_bit_cast(v8bf, *(const u32x4*)&Bs[(wn + f * 16 + fr) * 64 + ks * 32 + quad * 8]);
            }
#pragma unroll
            for (int i = 0; i < 4; i++)
#pragma unroll
                for (int j = 0; j < 4; j++)
                    acc[i][j] = __builtin_amdgcn_mfma_f32_16x16x32_bf16(af[i], bf[j], acc[i][j], 0, 0, 0);
        }
        __syncthreads();
    }

    // Epilogue: per-row partial Σexp(logit), Σlogit (logits<=30 -> fp32 sum safe, no max-sub)
#pragma unroll
    for (int i = 0; i < 4; i++) {
#pragma unroll
        for (int r = 0; r < 4; r++) {
            const int ml = wm + i * 16 + quad * 4 + r;
            const int mg = bm * 128 + ml;
            const int lab = label[mg];
            float esum = 0.f, lsum = 0.f;
#pragma unroll
            for (int j = 0; j < 4; j++) {
                const int ng = bn * 128 + wn + j * 16 + fr;
                if (ng < NCLS) {
                    float c = acc[i][j][r];
                    float logit;
                    if (ng == lab) {
                        float sine = sqrtf(clampf(1.f - c * c, 0.f, 1.f));
                        float phi = c * F_COS_M - sine * F_SIN_M;
                        float val = ((c - F_TH) > 0.f) ? phi : (c - F_MM);
                        logit = F_S * val;
                        philab[mg] = logit;
                    } else {
                        logit = F_S * c;
                    }
                    esum += __expf(logit);
                    lsum += logit;
                }
            }
#pragma unroll
            for (int off = 1; off < 16; off <<= 1) {
                esum += __shfl_xor(esum, off, 64);
                lsum += __shfl_xor(lsum, off, 64);
            }
            if (fr == 0) {
                atomicAdd(&red_e[ml], esum);
                atomicAdd(&red_l[ml], lsum);
            }
        }
    }
    __syncthreads();
    if (t < 128) {
        atomicAdd(&sumexp[bm * 128 + t], red_e[t]);
        atomicAdd(&sumlogit[bm * 128 + t], red_l[t]);
    }
}

// ============ CC dual GEMM (128x64 tile, BK=32) + fused row stats + last-block apm/zneg ============
__global__ __launch_bounds__(256) void gemm_cc_kernel(const u16* __restrict__ A,
                                                      const u16* __restrict__ Bq,
                                                      const u16* __restrict__ Bk,
                                                      const int* __restrict__ label,
                                                      float* __restrict__ sim,
                                                      float* __restrict__ msum,
                                                      float* __restrict__ mcnt,
                                                      float* __restrict__ ap,
                                                      float* __restrict__ cos_apm,
                                                      float* __restrict__ sin_apm,
                                                      float* __restrict__ zneg,
                                                      unsigned* __restrict__ tick) {
    __shared__ __align__(16) u16 As[128 * 32];   // 8 KB
    __shared__ __align__(16) u16 Qs[64 * 32];    // 4 KB
    __shared__ __align__(16) u16 Ks[64 * 32];    // 4 KB
    __shared__ float red_ms[128];
    __shared__ float red_mc[128];
    __shared__ float sh[4];
    __shared__ int slast;

    const int t = threadIdx.x;
    const int lane = t & 63, wave = t >> 6;
    const int wm = (wave >> 1) * 64, wn = (wave & 1) * 32;
    const int fr = lane & 15, quad = lane >> 4;
    const int bm = blockIdx.x, bn = blockIdx.y;

    if (t < 128) { red_ms[t] = 0.f; red_mc[t] = 0.f; }

    const int srow = t >> 2;  // 0..63
    const int sch  = t & 3;   // 16B chunk within 64B row-slice
    const u16* ag = A  + (size_t)(bm * 128 + srow) * DIM + sch * 8;
    const u16* qg = Bq + (size_t)(bn * 64 + srow) * DIM + sch * 8;
    const u16* kg = Bk + (size_t)(bn * 64 + srow) * DIM + sch * 8;
    u16* al = &As[srow * 32 + sch * 8];
    u16* ql = &Qs[srow * 32 + sch * 8];
    u16* kl = &Ks[srow * 32 + sch * 8];

    f32x4 aq[4][2] = {};
    f32x4 ak[4][2] = {};

    for (int k0 = 0; k0 < DIM; k0 += 32) {
        glds16(ag + k0, al);
        glds16(ag + (size_t)64 * DIM + k0, al + 64 * 32);
        glds16(qg + k0, ql);
        glds16(kg + k0, kl);
        __syncthreads();
        v8bf af[4], qf[2], kf[2];
#pragma unroll
        for (int f = 0; f < 4; f++)
            af[f] = __builtin_bit_cast(v8bf, *(const u32x4*)&As[(wm + f * 16 + fr) * 32 + quad * 8]);
#pragma unroll
        for (int f = 0; f < 2; f++) {
            qf[f] = __builtin_bit_cast(v8bf, *(const u32x4*)&Qs[(wn + f * 16 + fr) * 32 + quad * 8]);
            kf[f] = __builtin_bit_cast(v8bf, *(const u32x4*)&Ks[(wn + f * 16 + fr) * 32 + quad * 8]);
        }
#pragma unroll
        for (int i = 0; i < 4; i++)
#pragma unroll
            for (int j = 0; j < 2; j++) {
                aq[i][j] = __builtin_amdgcn_mfma_f32_16x16x32_bf16(af[i], qf[j], aq[i][j], 0, 0, 0);
                ak[i][j] = __builtin_amdgcn_mfma_f32_16x16x32_bf16(af[i], kf[j], ak[i][j], 0, 0, 0);
            }
        __syncthreads();
    }

    int lab_n[2];
#pragma unroll
    for (int j = 0; j < 2; j++) lab_n[j] = label[bn * 64 + wn + j * 16 + fr];

#pragma unroll
    for (int i = 0; i < 4; i++) {
#pragma unroll
        for (int r = 0; r < 4; r++) {
            const int ml = wm + i * 16 + quad * 4 + r;
            const int mg = bm * 128 + ml;
            const int lm = label[mg];
            float ms = 0.f, mc = 0.f;
#pragma unroll
            for (int j = 0; j < 2; j++) {
                const int ng = bn * 64 + wn + j * 16 + fr;
                float s = aq[i][j][r] * ak[i][j][r];
                sim[(size_t)mg * BATCH + ng] = s;
                if (lab_n[j] == lm) { ms += s; mc += 1.f; }
                if (mg == ng)
                    __hip_atomic_store(&ap[mg], s, __ATOMIC_RELAXED, __HIP_MEMORY_SCOPE_AGENT);
            }
#pragma unroll
            for (int off = 1; off < 16; off <<= 1) {
                ms += __shfl_xor(ms, off, 64);
                mc += __shfl_xor(mc, off, 64);
            }
            if (fr == 0) {
                atomicAdd(&red_ms[ml], ms);
                atomicAdd(&red_mc[ml], mc);
            }
        }
    }
    __syncthreads();
    if (t < 128) {
        atomicAdd(&msum[bm * 128 + t], red_ms[t]);
        atomicAdd(&mcnt[bm * 128 + t], red_mc[t]);
    }
    __syncthreads();
    if (t == 0) {
        __threadfence();
        unsigned old = atomicAdd(tick, 1u);
        slast = (old == gridDim.x * gridDim.y - 1) ? 1 : 0;
    }
    __syncthreads();
    if (slast) {   // last block: finalize apm stats + logneg -> zneg
        __threadfence();
        float accN = 0.f;
        for (int i = t; i < BATCH; i += 256) {
            float msv = __hip_atomic_load(&msum[i], __ATOMIC_RELAXED, __HIP_MEMORY_SCOPE_AGENT);
            float mcv = __hip_atomic_load(&mcnt[i], __ATOMIC_RELAXED, __HIP_MEMORY_SCOPE_AGENT);
            float apv = __hip_atomic_load(&ap[i],   __ATOMIC_RELAXED, __HIP_MEMORY_SCOPE_AGENT);
            float apm = msv / mcv;
            float cam = clampf(apm, 0.f, 1.f);
            float sam = sqrtf(clampf(1.f - cam, 0.f, 1.f));
            cos_apm[i] = cam;
            sin_apm[i] = sam;
            float cap = clampf(apv, 0.f, 1.f);
            float sap = sqrtf(clampf(1.f - cap, 0.f, 1.f));
            float ppc = cap * cam - sap * sam;
            float pps = sqrtf(clampf(1.f - ppc, 0.f, 1.f));
            float phi_pm = ppc * F_COS_M - pps * F_SIN_M;
            accN += __expf(1.f - phi_pm);
        }
        accN = blk_sum(accN, sh, t);
        if (t == 0) zneg[0] = accN;
    }
}

// ============ CC masked Σexp(phi_nm) + last-block final loss ============
__global__ __launch_bounds__(256) void cc_lse_kernel(const float* __restrict__ sim,
                                                     const int* __restrict__ label,
                                                     const float* __restrict__ cos_apm,
                                                     const float* __restrict__ sin_apm,
                                                     const float* __restrict__ zneg,
                                                     const float* __restrict__ sumexp,
                                                     const float* __restrict__ sumlogit,
                                                     const float* __restrict__ philab,
                                                     float* __restrict__ zn,
                                                     unsigned* __restrict__ tick,
                                                     float* __restrict__ out) {
    __shared__ float sh[4];
    __shared__ int slast;
    const int i = blockIdx.x, t = threadIdx.x;
    const int li = label[i];
    float acc = 0.f;
    const f32x4* simr = (const f32x4*)(sim + (size_t)i * BATCH);
    const f32x4* ca4p = (const f32x4*)cos_apm;
    const f32x4* sa4p = (const f32x4*)sin_apm;
    for (int jj = t; jj < BATCH / 4; jj += 256) {
        f32x4 s4 = simr[jj];
        int4 l4i = ((const int4*)label)[jj];
        const int* l4 = (const int*)&l4i;
        f32x4 ca4 = ca4p[jj];
        f32x4 sa4 = sa4p[jj];
#pragma unroll
        for (int e = 0; e < 4; e++) {
            if (l4[e] != li) {
                float can = clampf(s4[e], 0.f, 1.f);
                float san = sqrtf(clampf(1.f - can, 0.f, 1.f));
                float pns = san * ca4[e] + can * sa4[e];   // column-j broadcast
                float pnc = sqrtf(clampf(1.f - pns, 0.f, 1.f));
                acc += __expf(pns * F_COS_M - pnc * F_SIN_M);
            }
        }
    }
    acc = blk_sum(acc, sh, t);
    if (t == 0) {
        atomicAdd(zn, acc);
        __threadfence();
        unsigned old = atomicAdd(tick, 1u);
        slast = (old == (unsigned)(BATCH - 1)) ? 1 : 0;
    }
    __syncthreads();
    if (slast) {
        __threadfence();
        float accA = 0.f;
        for (int r = t; r < BATCH; r += 256) {
            float lse = logf(sumexp[r]);
            accA += 0.9f * (philab[r] - lse) + 1e-5f * (sumlogit[r] - (float)NCLS * lse);
        }
        accA = blk_sum(accA, sh, t);
        if (t == 0) {
            float znv = __hip_atomic_load(zn, __ATOMIC_RELAXED, __HIP_MEMORY_SCOPE_AGENT);
            float aam = -accA / (float)BATCH;
            float z = logf(znv) + logf(zneg[0]);
            float cc = (z > 0.f) ? (z + log1pf(__expf(-z))) : log1pf(__expf(z));
            out[0] = aam + cc;
        }
    }
}

extern "C" void kernel_launch(void* const* d_in, const int* in_sizes, int n_in,
                              void* d_out, int out_size, void* d_ws, size_t ws_size,
                              hipStream_t stream) {
    const float* x        = (const float*)d_in[0];
    const int*   label    = (const int*)d_in[1];
    const float* weight   = (const float*)d_in[2];
    const float* weight_m = (const float*)d_in[3];
    const float* weight_n = (const float*)d_in[4];
    float* out = (float*)d_out;
    char* ws = (char*)d_ws;

    const size_t o_xnb  = 0;
    const size_t o_wb   = o_xnb + (size_t)BATCH * DIM * 2;
    const size_t o_wqb  = o_wb  + (size_t)NPAD * DIM * 2;
    const size_t o_wkb  = o_wqb + (size_t)BATCH * DIM * 2;
    const size_t o_sim  = o_wkb + (size_t)BATCH * DIM * 2;
    const size_t o_misc = o_sim + (size_t)BATCH * BATCH * 4;

    u16* xnb = (u16*)(ws + o_xnb);
    u16* wb  = (u16*)(ws + o_wb);
    u16* wqb = (u16*)(ws + o_wqb);
    u16* wkb = (u16*)(ws + o_wkb);
    float* sim = (float*)(ws + o_sim);
    float* mf  = (float*)(ws + o_misc);

    // zeroed region (by norm_all, 33*256 = 8448 floats)
    float* sumexp   = mf;               // 2048
    float* sumlogit = mf + 2048;        // 2048
    float* msum     = mf + 4096;        // 2048
    float* mcnt     = mf + 6144;        // 2048
    float* zn       = mf + 8192;        // 1
    float* zneg     = mf + 8193;        // 1
    unsigned* tick_cc  = (unsigned*)(mf + 8194);
    unsigned* tick_lse = (unsigned*)(mf + 8195);
    // non-zeroed (fully overwritten every launch)
    float* philab  = mf + 8448;         // 2048
    float* ap      = mf + 10496;        // 2048
    float* cos_apm = mf + 12544;        // 2048
    float* sin_apm = mf + 14592;        // 2048

    norm_all_kernel<<<BATCH + NPAD + BATCH, 256, 0, stream>>>(
        x, weight, weight_m, weight_n, label, xnb, wb, wqb, wkb, mf);

    dim3 g_aam(BATCH / 128, NPAD / 128);   // (16, 79)
    gemm_aam_kernel<<<g_aam, 256, 0, stream>>>(xnb, wb, label, sumexp, sumlogit, philab);

    dim3 g_cc(BATCH / 128, BATCH / 64);    // (16, 32)
    gemm_cc_kernel<<<g_cc, 256, 0, stream>>>(xnb, wqb, wkb, label, sim,
                                             msum, mcnt, ap, cos_apm, sin_apm, zneg, tick_cc);

    cc_lse_kernel<<<BATCH, 256, 0, stream>>>(sim, label, cos_apm, sin_apm, zneg,
                                             sumexp, sumlogit, philab, zn, tick_lse, out);
}

// Round 3
// 206.964 us; speedup vs baseline: 1.2549x; 1.2549x over previous
//
#include <hip/hip_runtime.h>
#include <hip/hip_bf16.h>

typedef unsigned short u16;
typedef __bf16 v8bf __attribute__((ext_vector_type(8)));
typedef float f32x4 __attribute__((ext_vector_type(4)));
typedef unsigned int u32x4 __attribute__((ext_vector_type(4)));

constexpr int BATCH = 2048;
constexpr int DIM   = 512;
constexpr int NCLS  = 10000;
constexpr int NPAD  = 10112;   // 79 * 128

#define F_S     30.0f
#define F_COS_M 0.9800665778412416f
#define F_SIN_M 0.19866933079506122f
#define F_TH   (-0.9800665778412416f)
#define F_MM    0.03973386615901224f

static __device__ __forceinline__ float clampf(float v, float lo, float hi) {
    return fminf(fmaxf(v, lo), hi);
}
static __device__ __forceinline__ u16 f2bf(float v) {
    __hip_bfloat16 h = __float2bfloat16(v);
    return __builtin_bit_cast(unsigned short, h);
}
// async global->LDS, 16B per lane. LDS dest must be wave-uniform-base + lane*16.
static __device__ __forceinline__ void glds16(const void* g, void* l) {
    __builtin_amdgcn_global_load_lds(
        (const __attribute__((address_space(1))) unsigned int*)g,
        (__attribute__((address_space(3))) unsigned int*)l, 16, 0, 0);
}
static __device__ __forceinline__ float blk_sum(float v, float* sh, int t) {
#pragma unroll
    for (int o = 32; o > 0; o >>= 1) v += __shfl_down(v, o, 64);
    __syncthreads();
    if ((t & 63) == 0) sh[t >> 6] = v;
    __syncthreads();
    return sh[0] + sh[1] + sh[2] + sh[3];
}

// ============ merged normalize (x rows | w rows | gathered wm/wn rows) + acc zeroing ============
__global__ __launch_bounds__(256) void norm_all_kernel(const float* __restrict__ x,
                                                       const float* __restrict__ w,
                                                       const float* __restrict__ wm,
                                                       const float* __restrict__ wn,
                                                       const int* __restrict__ label,
                                                       u16* __restrict__ xnb,
                                                       u16* __restrict__ wb,
                                                       u16* __restrict__ wqb,
                                                       u16* __restrict__ wkb,
                                                       float* __restrict__ zacc) {
    __shared__ float sh[8];
    const int b = blockIdx.x, t = threadIdx.x;
    if (b < 33) zacc[b * 256 + t] = 0.f;   // zero accumulators (8448 >= 8193 used)

    if (b < BATCH) {
        const float* p = x + (size_t)b * DIM;
        float x0 = p[t], x1 = p[t + 256];
        float s = blk_sum(x0 * x0 + x1 * x1, sh, t);
        float inv = 1.0f / fmaxf(sqrtf(s), 1e-12f);
        xnb[(size_t)b * DIM + t]       = f2bf(x0 * inv);
        xnb[(size_t)b * DIM + t + 256] = f2bf(x1 * inv);
    } else if (b < BATCH + NPAD) {
        const int row = b - BATCH;
        if (row >= NCLS) {
            wb[(size_t)row * DIM + t] = 0;
            wb[(size_t)row * DIM + t + 256] = 0;
            return;
        }
        const float* p = w + (size_t)row * DIM;
        float x0 = p[t], x1 = p[t + 256];
        float s = blk_sum(x0 * x0 + x1 * x1, sh, t);
        float inv = 1.0f / fmaxf(sqrtf(s), 1e-12f);
        wb[(size_t)row * DIM + t]       = f2bf(x0 * inv);
        wb[(size_t)row * DIM + t + 256] = f2bf(x1 * inv);
    } else {
        const int i = b - (BATCH + NPAD);
        const int g = label[i];
        const float* pq = wm + (size_t)g * DIM;
        const float* pk = wn + (size_t)g * DIM;
        float q0 = pq[t], q1 = pq[t + 256];
        float k0 = pk[t], k1 = pk[t + 256];
        float sq = blk_sum(q0 * q0 + q1 * q1, sh, t);
        float sk = blk_sum(k0 * k0 + k1 * k1, sh + 4, t);
        float iq = 1.0f / fmaxf(sqrtf(sq), 1e-12f);
        float ik = 1.0f / fmaxf(sqrtf(sk), 1e-12f);
        wqb[(size_t)i * DIM + t]       = f2bf(q0 * iq);
        wqb[(size_t)i * DIM + t + 256] = f2bf(q1 * iq);
        wkb[(size_t)i * DIM + t]       = f2bf(k0 * ik);
        wkb[(size_t)i * DIM + t + 256] = f2bf(k1 * ik);
    }
}

// ============ AAM GEMM (128x128 tile, BK=64, global_load_lds staging) + fused softmax sums ============
__global__ __launch_bounds__(256) void gemm_aam_kernel(const u16* __restrict__ A,
                                                       const u16* __restrict__ B,
                                                       const int* __restrict__ label,
                                                       float* __restrict__ sumexp,
                                                       float* __restrict__ sumlogit,
                                                       float* __restrict__ philab) {
    __shared__ __align__(16) u16 As[128 * 64];   // 16 KB, unpadded (glds requirement)
    __shared__ __align__(16) u16 Bs[128 * 64];
    __shared__ float red_e[128];
    __shared__ float red_l[128];

    const int t = threadIdx.x;
    const int lane = t & 63, wave = t >> 6;
    const int wm = (wave >> 1) * 64, wn = (wave & 1) * 64;
    const int fr = lane & 15, quad = lane >> 4;
    const int bm = blockIdx.x, bn = blockIdx.y;

    if (t < 128) { red_e[t] = 0.f; red_l[t] = 0.f; }

    const int srow = t >> 3;
    const int sch  = t & 7;
    const u16* ag = A + (size_t)(bm * 128 + srow) * DIM + sch * 8;
    const u16* bg = B + (size_t)(bn * 128 + srow) * DIM + sch * 8;
    u16* al = &As[srow * 64 + sch * 8];
    u16* bl = &Bs[srow * 64 + sch * 8];

    f32x4 acc[4][4] = {};

    for (int k0 = 0; k0 < DIM; k0 += 64) {
#pragma unroll
        for (int r = 0; r < 4; r++) {
            glds16(ag + (size_t)(r * 32) * DIM + k0, al + r * 32 * 64);
            glds16(bg + (size_t)(r * 32) * DIM + k0, bl + r * 32 * 64);
        }
        __syncthreads();
#pragma unroll
        for (int ks = 0; ks < 2; ks++) {
            v8bf af[4], bf[4];
#pragma unroll
            for (int f = 0; f < 4; f++) {
                af[f] = __builtin_bit_cast(v8bf, *(const u32x4*)&As[(wm + f * 16 + fr) * 64 + ks * 32 + quad * 8]);
                bf[f] = __builtin_bit_cast(v8bf, *(const u32x4*)&Bs[(wn + f * 16 + fr) * 64 + ks * 32 + quad * 8]);
            }
#pragma unroll
            for (int i = 0; i < 4; i++)
#pragma unroll
                for (int j = 0; j < 4; j++)
                    acc[i][j] = __builtin_amdgcn_mfma_f32_16x16x32_bf16(af[i], bf[j], acc[i][j], 0, 0, 0);
        }
        __syncthreads();
    }

#pragma unroll
    for (int i = 0; i < 4; i++) {
#pragma unroll
        for (int r = 0; r < 4; r++) {
            const int ml = wm + i * 16 + quad * 4 + r;
            const int mg = bm * 128 + ml;
            const int lab = label[mg];
            float esum = 0.f, lsum = 0.f;
#pragma unroll
            for (int j = 0; j < 4; j++) {
                const int ng = bn * 128 + wn + j * 16 + fr;
                if (ng < NCLS) {
                    float c = acc[i][j][r];
                    float logit;
                    if (ng == lab) {
                        float sine = sqrtf(clampf(1.f - c * c, 0.f, 1.f));
                        float phi = c * F_COS_M - sine * F_SIN_M;
                        float val = ((c - F_TH) > 0.f) ? phi : (c - F_MM);
                        logit = F_S * val;
                        philab[mg] = logit;
                    } else {
                        logit = F_S * c;
                    }
                    esum += __expf(logit);
                    lsum += logit;
                }
            }
#pragma unroll
            for (int off = 1; off < 16; off <<= 1) {
                esum += __shfl_xor(esum, off, 64);
                lsum += __shfl_xor(lsum, off, 64);
            }
            if (fr == 0) {
                atomicAdd(&red_e[ml], esum);
                atomicAdd(&red_l[ml], lsum);
            }
        }
    }
    __syncthreads();
    if (t < 128) {
        atomicAdd(&sumexp[bm * 128 + t], red_e[t]);
        atomicAdd(&sumlogit[bm * 128 + t], red_l[t]);
    }
}

// ============ CC dual GEMM (128x64 tile, BK=32) + fused row sums (no fences/tickets) ============
__global__ __launch_bounds__(256) void gemm_cc_kernel(const u16* __restrict__ A,
                                                      const u16* __restrict__ Bq,
                                                      const u16* __restrict__ Bk,
                                                      const int* __restrict__ label,
                                                      float* __restrict__ sim,
                                                      float* __restrict__ msum,
                                                      float* __restrict__ mcnt,
                                                      float* __restrict__ ap) {
    __shared__ __align__(16) u16 As[128 * 32];
    __shared__ __align__(16) u16 Qs[64 * 32];
    __shared__ __align__(16) u16 Ks[64 * 32];
    __shared__ float red_ms[128];
    __shared__ float red_mc[128];

    const int t = threadIdx.x;
    const int lane = t & 63, wave = t >> 6;
    const int wm = (wave >> 1) * 64, wn = (wave & 1) * 32;
    const int fr = lane & 15, quad = lane >> 4;
    const int bm = blockIdx.x, bn = blockIdx.y;

    if (t < 128) { red_ms[t] = 0.f; red_mc[t] = 0.f; }

    const int srow = t >> 2;
    const int sch  = t & 3;
    const u16* ag = A  + (size_t)(bm * 128 + srow) * DIM + sch * 8;
    const u16* qg = Bq + (size_t)(bn * 64 + srow) * DIM + sch * 8;
    const u16* kg = Bk + (size_t)(bn * 64 + srow) * DIM + sch * 8;
    u16* al = &As[srow * 32 + sch * 8];
    u16* ql = &Qs[srow * 32 + sch * 8];
    u16* kl = &Ks[srow * 32 + sch * 8];

    f32x4 aq[4][2] = {};
    f32x4 ak[4][2] = {};

    for (int k0 = 0; k0 < DIM; k0 += 32) {
        glds16(ag + k0, al);
        glds16(ag + (size_t)64 * DIM + k0, al + 64 * 32);
        glds16(qg + k0, ql);
        glds16(kg + k0, kl);
        __syncthreads();
        v8bf af[4], qf[2], kf[2];
#pragma unroll
        for (int f = 0; f < 4; f++)
            af[f] = __builtin_bit_cast(v8bf, *(const u32x4*)&As[(wm + f * 16 + fr) * 32 + quad * 8]);
#pragma unroll
        for (int f = 0; f < 2; f++) {
            qf[f] = __builtin_bit_cast(v8bf, *(const u32x4*)&Qs[(wn + f * 16 + fr) * 32 + quad * 8]);
            kf[f] = __builtin_bit_cast(v8bf, *(const u32x4*)&Ks[(wn + f * 16 + fr) * 32 + quad * 8]);
        }
#pragma unroll
        for (int i = 0; i < 4; i++)
#pragma unroll
            for (int j = 0; j < 2; j++) {
                aq[i][j] = __builtin_amdgcn_mfma_f32_16x16x32_bf16(af[i], qf[j], aq[i][j], 0, 0, 0);
                ak[i][j] = __builtin_amdgcn_mfma_f32_16x16x32_bf16(af[i], kf[j], ak[i][j], 0, 0, 0);
            }
        __syncthreads();
    }

    int lab_n[2];
#pragma unroll
    for (int j = 0; j < 2; j++) lab_n[j] = label[bn * 64 + wn + j * 16 + fr];

#pragma unroll
    for (int i = 0; i < 4; i++) {
#pragma unroll
        for (int r = 0; r < 4; r++) {
            const int ml = wm + i * 16 + quad * 4 + r;
            const int mg = bm * 128 + ml;
            const int lm = label[mg];
            float ms = 0.f, mc = 0.f;
#pragma unroll
            for (int j = 0; j < 2; j++) {
                const int ng = bn * 64 + wn + j * 16 + fr;
                float s = aq[i][j][r] * ak[i][j][r];
                sim[(size_t)mg * BATCH + ng] = s;
                if (lab_n[j] == lm) { ms += s; mc += 1.f; }
                if (mg == ng) ap[mg] = s;   // unique writer; read next kernel (boundary orders)
            }
#pragma unroll
            for (int off = 1; off < 16; off <<= 1) {
                ms += __shfl_xor(ms, off, 64);
                mc += __shfl_xor(mc, off, 64);
            }
            if (fr == 0) {
                atomicAdd(&red_ms[ml], ms);
                atomicAdd(&red_mc[ml], mc);
            }
        }
    }
    __syncthreads();
    if (t < 128) {
        atomicAdd(&msum[bm * 128 + t], red_ms[t]);
        atomicAdd(&mcnt[bm * 128 + t], red_mc[t]);
    }
}

// ============ CC pass 2: masked Σexp(phi_nm) over sim; apm recomputed into LDS per block ============
// 256 blocks x 8 rows each; ONE fire-and-forget atomic per block; no fences.
__global__ __launch_bounds__(256) void cc_pass2_kernel(const float* __restrict__ sim,
                                                       const int* __restrict__ label,
                                                       const float* __restrict__ msum,
                                                       const float* __restrict__ mcnt,
                                                       const float* __restrict__ ap,
                                                       float* __restrict__ zn,
                                                       float* __restrict__ zneg) {
    __shared__ __align__(16) float cam_s[BATCH];
    __shared__ __align__(16) float sam_s[BATCH];
    __shared__ float sh[4];
    const int t = threadIdx.x, b = blockIdx.x;

    for (int j = t; j < BATCH; j += 256) {
        float cam = clampf(msum[j] / mcnt[j], 0.f, 1.f);   // mcnt >= 1 (diagonal)
        cam_s[j] = cam;
        sam_s[j] = sqrtf(clampf(1.f - cam, 0.f, 1.f));
    }
    __syncthreads();

    float acc = 0.f;
#pragma unroll
    for (int row = 0; row < 8; row++) {
        const int i = b * 8 + row;
        const int li = label[i];
        const f32x4* simr = (const f32x4*)(sim + (size_t)i * BATCH);
        const f32x4* cap4 = (const f32x4*)cam_s;
        const f32x4* sap4 = (const f32x4*)sam_s;
#pragma unroll
        for (int k = 0; k < 2; k++) {
            const int jj = t + k * 256;
            f32x4 s4 = simr[jj];
            int4 l4i = ((const int4*)label)[jj];
            const int* l4 = (const int*)&l4i;
            f32x4 ca4 = cap4[jj];
            f32x4 sa4 = sap4[jj];
#pragma unroll
            for (int e = 0; e < 4; e++) {
                if (l4[e] != li) {
                    float can = clampf(s4[e], 0.f, 1.f);
                    float san = sqrtf(clampf(1.f - can, 0.f, 1.f));
                    float pns = san * ca4[e] + can * sa4[e];   // column-j broadcast
                    float pnc = sqrtf(clampf(1.f - pns, 0.f, 1.f));
                    acc += __expf(pns * F_COS_M - pnc * F_SIN_M);
                }
            }
        }
    }
    acc = blk_sum(acc, sh, t);
    if (t == 0) atomicAdd(zn, acc);

    if (b == 0) {   // logit_neg partition: Σexp(1 - phi_pm)
        float accN = 0.f;
        for (int i = t; i < BATCH; i += 256) {
            float cam = cam_s[i], sam = sam_s[i];
            float cap = clampf(ap[i], 0.f, 1.f);
            float sap = sqrtf(clampf(1.f - cap, 0.f, 1.f));
            float ppc = cap * cam - sap * sam;
            float pps = sqrtf(clampf(1.f - ppc, 0.f, 1.f));
            accN += __expf(1.f - (ppc * F_COS_M - pps * F_SIN_M));
        }
        accN = blk_sum(accN, sh, t);
        if (t == 0) zneg[0] = accN;
    }
}

// ============ finalize: single block ============
__global__ __launch_bounds__(256) void finalize_kernel(const float* __restrict__ sumexp,
                                                       const float* __restrict__ sumlogit,
                                                       const float* __restrict__ philab,
                                                       const float* __restrict__ zn,
                                                       const float* __restrict__ zneg,
                                                       float* __restrict__ out) {
    __shared__ float sh[4];
    const int t = threadIdx.x;
    float accA = 0.f;
    for (int r = t; r < BATCH; r += 256) {
        float lse = logf(sumexp[r]);
        accA += 0.9f * (philab[r] - lse) + 1e-5f * (sumlogit[r] - (float)NCLS * lse);
    }
    accA = blk_sum(accA, sh, t);
    if (t == 0) {
        float aam = -accA / (float)BATCH;
        float z = logf(zn[0]) + logf(zneg[0]);
        float cc = (z > 0.f) ? (z + log1pf(__expf(-z))) : log1pf(__expf(z));
        out[0] = aam + cc;
    }
}

extern "C" void kernel_launch(void* const* d_in, const int* in_sizes, int n_in,
                              void* d_out, int out_size, void* d_ws, size_t ws_size,
                              hipStream_t stream) {
    const float* x        = (const float*)d_in[0];
    const int*   label    = (const int*)d_in[1];
    const float* weight   = (const float*)d_in[2];
    const float* weight_m = (const float*)d_in[3];
    const float* weight_n = (const float*)d_in[4];
    float* out = (float*)d_out;
    char* ws = (char*)d_ws;

    const size_t o_xnb  = 0;
    const size_t o_wb   = o_xnb + (size_t)BATCH * DIM * 2;
    const size_t o_wqb  = o_wb  + (size_t)NPAD * DIM * 2;
    const size_t o_wkb  = o_wqb + (size_t)BATCH * DIM * 2;
    const size_t o_sim  = o_wkb + (size_t)BATCH * DIM * 2;
    const size_t o_misc = o_sim + (size_t)BATCH * BATCH * 4;

    u16* xnb = (u16*)(ws + o_xnb);
    u16* wb  = (u16*)(ws + o_wb);
    u16* wqb = (u16*)(ws + o_wqb);
    u16* wkb = (u16*)(ws + o_wkb);
    float* sim = (float*)(ws + o_sim);
    float* mf  = (float*)(ws + o_misc);

    // zeroed by norm_all (33*256 = 8448 floats)
    float* sumexp   = mf;               // 2048
    float* sumlogit = mf + 2048;        // 2048
    float* msum     = mf + 4096;        // 2048
    float* mcnt     = mf + 6144;        // 2048
    float* zn       = mf + 8192;        // 1
    float* zneg     = mf + 8193;        // 1 (plain store, needs no zeroing)
    // non-zeroed (fully overwritten every launch)
    float* philab  = mf + 8448;         // 2048
    float* ap      = mf + 10496;        // 2048

    norm_all_kernel<<<BATCH + NPAD + BATCH, 256, 0, stream>>>(
        x, weight, weight_m, weight_n, label, xnb, wb, wqb, wkb, mf);

    dim3 g_aam(BATCH / 128, NPAD / 128);   // (16, 79)
    gemm_aam_kernel<<<g_aam, 256, 0, stream>>>(xnb, wb, label, sumexp, sumlogit, philab);

    dim3 g_cc(BATCH / 128, BATCH / 64);    // (16, 32)
    gemm_cc_kernel<<<g_cc, 256, 0, stream>>>(xnb, wqb, wkb, label, sim, msum, mcnt, ap);

    cc_pass2_kernel<<<256, 256, 0, stream>>>(sim, label, msum, mcnt, ap, zn, zneg);

    finalize_kernel<<<1, 256, 0, stream>>>(sumexp, sumlogit, philab, zn, zneg, out);
}

// Round 4
// 199.097 us; speedup vs baseline: 1.3045x; 1.0395x over previous
//
#include <hip/hip_runtime.h>
#include <hip/hip_bf16.h>

typedef unsigned short u16;
typedef unsigned int u32;
typedef __bf16 v8bf __attribute__((ext_vector_type(8)));
typedef float f32x4 __attribute__((ext_vector_type(4)));
typedef unsigned int u32x4 __attribute__((ext_vector_type(4)));

constexpr int BATCH = 2048;
constexpr int DIM   = 512;
constexpr int NCLS  = 10000;
constexpr int NPAD  = 10112;   // 79 * 128

#define F_S     30.0f
#define F_COS_M 0.9800665778412416f
#define F_SIN_M 0.19866933079506122f
#define F_TH   (-0.9800665778412416f)
#define F_MM    0.03973386615901224f

static __device__ __forceinline__ float clampf(float v, float lo, float hi) {
    return fminf(fmaxf(v, lo), hi);
}
static __device__ __forceinline__ u16 f2bf(float v) {
    __hip_bfloat16 h = __float2bfloat16(v);
    return __builtin_bit_cast(unsigned short, h);
}
// async global->LDS, 16B per lane. LDS dest is wave-uniform base + lane*16.
static __device__ __forceinline__ void glds16(const void* g, void* l) {
    __builtin_amdgcn_global_load_lds(
        (const __attribute__((address_space(1))) unsigned int*)g,
        (__attribute__((address_space(3))) unsigned int*)l, 16, 0, 0);
}
static __device__ __forceinline__ float blk_sum(float v, float* sh, int t) {
#pragma unroll
    for (int o = 32; o > 0; o >>= 1) v += __shfl_down(v, o, 64);
    __syncthreads();
    if ((t & 63) == 0) sh[t >> 6] = v;
    __syncthreads();
    return sh[0] + sh[1] + sh[2] + sh[3];
}

// ============ merged normalize (x rows | w rows | gathered wm/wn rows) + acc zeroing ============
// float2 loads, packed bf16x2 u32 stores.
__global__ __launch_bounds__(256) void norm_all_kernel(const float* __restrict__ x,
                                                       const float* __restrict__ w,
                                                       const float* __restrict__ wm,
                                                       const float* __restrict__ wn,
                                                       const int* __restrict__ label,
                                                       u32* __restrict__ xnb,
                                                       u32* __restrict__ wb,
                                                       u32* __restrict__ wqb,
                                                       u32* __restrict__ wkb,
                                                       float* __restrict__ zacc) {
    __shared__ float sh[8];
    const int b = blockIdx.x, t = threadIdx.x;
    if (b < 33) zacc[b * 256 + t] = 0.f;   // zero accumulators (8448 >= 8193 used)

    if (b < BATCH) {
        const float2 v = ((const float2*)(x + (size_t)b * DIM))[t];
        float s = blk_sum(v.x * v.x + v.y * v.y, sh, t);
        float inv = 1.0f / fmaxf(sqrtf(s), 1e-12f);
        xnb[(size_t)b * 256 + t] = (u32)f2bf(v.x * inv) | ((u32)f2bf(v.y * inv) << 16);
    } else if (b < BATCH + NPAD) {
        const int row = b - BATCH;
        if (row >= NCLS) {  // uniform per block
            wb[(size_t)row * 256 + t] = 0;
            return;
        }
        const float2 v = ((const float2*)(w + (size_t)row * DIM))[t];
        float s = blk_sum(v.x * v.x + v.y * v.y, sh, t);
        float inv = 1.0f / fmaxf(sqrtf(s), 1e-12f);
        wb[(size_t)row * 256 + t] = (u32)f2bf(v.x * inv) | ((u32)f2bf(v.y * inv) << 16);
    } else {
        const int i = b - (BATCH + NPAD);
        const int g = label[i];
        const float2 q = ((const float2*)(wm + (size_t)g * DIM))[t];
        const float2 k = ((const float2*)(wn + (size_t)g * DIM))[t];
        float sq = blk_sum(q.x * q.x + q.y * q.y, sh, t);
        float sk = blk_sum(k.x * k.x + k.y * k.y, sh + 4, t);
        float iq = 1.0f / fmaxf(sqrtf(sq), 1e-12f);
        float ik = 1.0f / fmaxf(sqrtf(sk), 1e-12f);
        wqb[(size_t)i * 256 + t] = (u32)f2bf(q.x * iq) | ((u32)f2bf(q.y * iq) << 16);
        wkb[(size_t)i * 256 + t] = (u32)f2bf(k.x * ik) | ((u32)f2bf(k.y * ik) << 16);
    }
}

// ============ AAM GEMM (128x128, BK=64, glds + XOR-swizzled LDS) + fused softmax sums ============
// Swizzle: staging lane t stores global chunk ((t&7)^((t>>3)&7)) at LDS slot (t&7) of row (t>>3).
// Reader fetches slot ((ks*4+quad)^(fr&7)) -> all 8 bank-groups hit by exactly 8 lanes: conflict-free.
__global__ __launch_bounds__(256) void gemm_aam_kernel(const u16* __restrict__ A,
                                                       const u16* __restrict__ B,
                                                       const int* __restrict__ label,
                                                       float* __restrict__ sumexp,
                                                       float* __restrict__ sumlogit,
                                                       float* __restrict__ philab) {
    __shared__ __align__(16) u16 As[128 * 64];   // 16 KB, unpadded (glds requirement)
    __shared__ __align__(16) u16 Bs[128 * 64];
    __shared__ float red_e[128];
    __shared__ float red_l[128];

    const int t = threadIdx.x;
    const int lane = t & 63, wave = t >> 6;
    const int wm = (wave >> 1) * 64, wn = (wave & 1) * 64;
    const int fr = lane & 15, quad = lane >> 4;
    const int swz = fr & 7;
    const int bm = blockIdx.x, bn = blockIdx.y;

    if (t < 128) { red_e[t] = 0.f; red_l[t] = 0.f; }

    const int srow = t >> 3;                    // 0..31 (+r*32 per shot)
    const int scg  = (t & 7) ^ (srow & 7);      // swizzled global chunk
    const u16* ag = A + (size_t)(bm * 128 + srow) * DIM + scg * 8;
    const u16* bg = B + (size_t)(bn * 128 + srow) * DIM + scg * 8;
    u16* al = &As[t * 8];                       // linear LDS dest (lane*16 B)
    u16* bl = &Bs[t * 8];

    f32x4 acc[4][4] = {};

    for (int k0 = 0; k0 < DIM; k0 += 64) {
#pragma unroll
        for (int r = 0; r < 4; r++) {
            glds16(ag + (size_t)(r * 32) * DIM + k0, al + r * 2048);
            glds16(bg + (size_t)(r * 32) * DIM + k0, bl + r * 2048);
        }
        __syncthreads();
#pragma unroll
        for (int ks = 0; ks < 2; ks++) {
            v8bf af[4], bf[4];
#pragma unroll
            for (int f = 0; f < 4; f++) {
                const int slot = ((ks << 2) | quad) ^ swz;
                af[f] = __builtin_bit_cast(v8bf, *(const u32x4*)&As[(wm + f * 16 + fr) * 64 + slot * 8]);
                bf[f] = __builtin_bit_cast(v8bf, *(const u32x4*)&Bs[(wn + f * 16 + fr) * 64 + slot * 8]);
            }
#pragma unroll
            for (int i = 0; i < 4; i++)
#pragma unroll
                for (int j = 0; j < 4; j++)
                    acc[i][j] = __builtin_amdgcn_mfma_f32_16x16x32_bf16(af[i], bf[j], acc[i][j], 0, 0, 0);
        }
        __syncthreads();
    }

    // Epilogue: per-row partial Σexp(logit), Σlogit (logits<=30 -> fp32 sum safe, no max-sub)
#pragma unroll
    for (int i = 0; i < 4; i++) {
#pragma unroll
        for (int r = 0; r < 4; r++) {
            const int ml = wm + i * 16 + quad * 4 + r;
            const int mg = bm * 128 + ml;
            const int lab = label[mg];
            float esum = 0.f, lsum = 0.f;
#pragma unroll
            for (int j = 0; j < 4; j++) {
                const int ng = bn * 128 + wn + j * 16 + fr;
                if (ng < NCLS) {
                    float c = acc[i][j][r];
                    float logit;
                    if (ng == lab) {
                        float sine = sqrtf(clampf(1.f - c * c, 0.f, 1.f));
                        float phi = c * F_COS_M - sine * F_SIN_M;
                        float val = ((c - F_TH) > 0.f) ? phi : (c - F_MM);
                        logit = F_S * val;
                        philab[mg] = logit;
                    } else {
                        logit = F_S * c;
                    }
                    esum += __expf(logit);
                    lsum += logit;
                }
            }
#pragma unroll
            for (int off = 1; off < 16; off <<= 1) {
                esum += __shfl_xor(esum, off, 64);
                lsum += __shfl_xor(lsum, off, 64);
            }
            if (fr == 0) {
                atomicAdd(&red_e[ml], esum);
                atomicAdd(&red_l[ml], lsum);
            }
        }
    }
    __syncthreads();
    if (t < 128) {
        atomicAdd(&sumexp[bm * 128 + t], red_e[t]);
        atomicAdd(&sumlogit[bm * 128 + t], red_l[t]);
    }
}

// ============ CC dual GEMM (128x64, BK=32) + fused row sums ============
// 64 B rows: natural bank distribution is already balanced (bg = quad + 4*(row&1)); no swizzle needed.
__global__ __launch_bounds__(256) void gemm_cc_kernel(const u16* __restrict__ A,
                                                      const u16* __restrict__ Bq,
                                                      const u16* __restrict__ Bk,
                                                      const int* __restrict__ label,
                                                      float* __restrict__ sim,
                                                      float* __restrict__ msum,
                                                      float* __restrict__ mcnt,
                                                      float* __restrict__ ap) {
    __shared__ __align__(16) u16 As[128 * 32];
    __shared__ __align__(16) u16 Qs[64 * 32];
    __shared__ __align__(16) u16 Ks[64 * 32];
    __shared__ float red_ms[128];
    __shared__ float red_mc[128];

    const int t = threadIdx.x;
    const int lane = t & 63, wave = t >> 6;
    const int wm = (wave >> 1) * 64, wn = (wave & 1) * 32;
    const int fr = lane & 15, quad = lane >> 4;
    const int bm = blockIdx.x, bn = blockIdx.y;

    if (t < 128) { red_ms[t] = 0.f; red_mc[t] = 0.f; }

    const int srow = t >> 2;
    const int sch  = t & 3;
    const u16* ag = A  + (size_t)(bm * 128 + srow) * DIM + sch * 8;
    const u16* qg = Bq + (size_t)(bn * 64 + srow) * DIM + sch * 8;
    const u16* kg = Bk + (size_t)(bn * 64 + srow) * DIM + sch * 8;
    u16* al = &As[t * 8];
    u16* ql = &Qs[t * 8];
    u16* kl = &Ks[t * 8];

    f32x4 aq[4][2] = {};
    f32x4 ak[4][2] = {};

    for (int k0 = 0; k0 < DIM; k0 += 32) {
        glds16(ag + k0, al);
        glds16(ag + (size_t)64 * DIM + k0, al + 64 * 32);
        glds16(qg + k0, ql);
        glds16(kg + k0, kl);
        __syncthreads();
        v8bf af[4], qf[2], kf[2];
#pragma unroll
        for (int f = 0; f < 4; f++)
            af[f] = __builtin_bit_cast(v8bf, *(const u32x4*)&As[(wm + f * 16 + fr) * 32 + quad * 8]);
#pragma unroll
        for (int f = 0; f < 2; f++) {
            qf[f] = __builtin_bit_cast(v8bf, *(const u32x4*)&Qs[(wn + f * 16 + fr) * 32 + quad * 8]);
            kf[f] = __builtin_bit_cast(v8bf, *(const u32x4*)&Ks[(wn + f * 16 + fr) * 32 + quad * 8]);
        }
#pragma unroll
        for (int i = 0; i < 4; i++)
#pragma unroll
            for (int j = 0; j < 2; j++) {
                aq[i][j] = __builtin_amdgcn_mfma_f32_16x16x32_bf16(af[i], qf[j], aq[i][j], 0, 0, 0);
                ak[i][j] = __builtin_amdgcn_mfma_f32_16x16x32_bf16(af[i], kf[j], ak[i][j], 0, 0, 0);
            }
        __syncthreads();
    }

    int lab_n[2];
#pragma unroll
    for (int j = 0; j < 2; j++) lab_n[j] = label[bn * 64 + wn + j * 16 + fr];

#pragma unroll
    for (int i = 0; i < 4; i++) {
#pragma unroll
        for (int r = 0; r < 4; r++) {
            const int ml = wm + i * 16 + quad * 4 + r;
            const int mg = bm * 128 + ml;
            const int lm = label[mg];
            float ms = 0.f, mc = 0.f;
#pragma unroll
            for (int j = 0; j < 2; j++) {
                const int ng = bn * 64 + wn + j * 16 + fr;
                float s = aq[i][j][r] * ak[i][j][r];
                sim[(size_t)mg * BATCH + ng] = s;
                if (lab_n[j] == lm) { ms += s; mc += 1.f; }
                if (mg == ng) ap[mg] = s;   // unique writer; read next kernel (boundary orders)
            }
#pragma unroll
            for (int off = 1; off < 16; off <<= 1) {
                ms += __shfl_xor(ms, off, 64);
                mc += __shfl_xor(mc, off, 64);
            }
            if (fr == 0) {
                atomicAdd(&red_ms[ml], ms);
                atomicAdd(&red_mc[ml], mc);
            }
        }
    }
    __syncthreads();
    if (t < 128) {
        atomicAdd(&msum[bm * 128 + t], red_ms[t]);
        atomicAdd(&mcnt[bm * 128 + t], red_mc[t]);
    }
}

// ============ CC pass 2: masked Σexp(phi_nm); apm recomputed into LDS per block ============
__global__ __launch_bounds__(256) void cc_pass2_kernel(const float* __restrict__ sim,
                                                       const int* __restrict__ label,
                                                       const float* __restrict__ msum,
                                                       const float* __restrict__ mcnt,
                                                       const float* __restrict__ ap,
                                                       float* __restrict__ zn,
                                                       float* __restrict__ zneg) {
    __shared__ __align__(16) float cam_s[BATCH];
    __shared__ __align__(16) float sam_s[BATCH];
    __shared__ float sh[4];
    const int t = threadIdx.x, b = blockIdx.x;

    for (int j = t; j < BATCH; j += 256) {
        float cam = clampf(msum[j] / mcnt[j], 0.f, 1.f);   // mcnt >= 1 (diagonal)
        cam_s[j] = cam;
        sam_s[j] = sqrtf(clampf(1.f - cam, 0.f, 1.f));
    }
    __syncthreads();

    float acc = 0.f;
#pragma unroll
    for (int row = 0; row < 8; row++) {
        const int i = b * 8 + row;
        const int li = label[i];
        const f32x4* simr = (const f32x4*)(sim + (size_t)i * BATCH);
        const f32x4* cap4 = (const f32x4*)cam_s;
        const f32x4* sap4 = (const f32x4*)sam_s;
#pragma unroll
        for (int k = 0; k < 2; k++) {
            const int jj = t + k * 256;
            f32x4 s4 = simr[jj];
            int4 l4i = ((const int4*)label)[jj];
            const int* l4 = (const int*)&l4i;
            f32x4 ca4 = cap4[jj];
            f32x4 sa4 = sap4[jj];
#pragma unroll
            for (int e = 0; e < 4; e++) {
                if (l4[e] != li) {
                    float can = clampf(s4[e], 0.f, 1.f);
                    float san = sqrtf(clampf(1.f - can, 0.f, 1.f));
                    float pns = san * ca4[e] + can * sa4[e];   // column-j broadcast
                    float pnc = sqrtf(clampf(1.f - pns, 0.f, 1.f));
                    acc += __expf(pns * F_COS_M - pnc * F_SIN_M);
                }
            }
        }
    }
    acc = blk_sum(acc, sh, t);
    if (t == 0) atomicAdd(zn, acc);

    if (b == 0) {   // logit_neg partition: Σexp(1 - phi_pm)
        float accN = 0.f;
        for (int i = t; i < BATCH; i += 256) {
            float cam = cam_s[i], sam = sam_s[i];
            float cap = clampf(ap[i], 0.f, 1.f);
            float sap = sqrtf(clampf(1.f - cap, 0.f, 1.f));
            float ppc = cap * cam - sap * sam;
            float pps = sqrtf(clampf(1.f - ppc, 0.f, 1.f));
            accN += __expf(1.f - (ppc * F_COS_M - pps * F_SIN_M));
        }
        accN = blk_sum(accN, sh, t);
        if (t == 0) zneg[0] = accN;
    }
}

// ============ finalize: single block ============
__global__ __launch_bounds__(256) void finalize_kernel(const float* __restrict__ sumexp,
                                                       const float* __restrict__ sumlogit,
                                                       const float* __restrict__ philab,
                                                       const float* __restrict__ zn,
                                                       const float* __restrict__ zneg,
                                                       float* __restrict__ out) {
    __shared__ float sh[4];
    const int t = threadIdx.x;
    float accA = 0.f;
    for (int r = t; r < BATCH; r += 256) {
        float lse = logf(sumexp[r]);
        accA += 0.9f * (philab[r] - lse) + 1e-5f * (sumlogit[r] - (float)NCLS * lse);
    }
    accA = blk_sum(accA, sh, t);
    if (t == 0) {
        float aam = -accA / (float)BATCH;
        float z = logf(zn[0]) + logf(zneg[0]);
        float cc = (z > 0.f) ? (z + log1pf(__expf(-z))) : log1pf(__expf(z));
        out[0] = aam + cc;
    }
}

extern "C" void kernel_launch(void* const* d_in, const int* in_sizes, int n_in,
                              void* d_out, int out_size, void* d_ws, size_t ws_size,
                              hipStream_t stream) {
    const float* x        = (const float*)d_in[0];
    const int*   label    = (const int*)d_in[1];
    const float* weight   = (const float*)d_in[2];
    const float* weight_m = (const float*)d_in[3];
    const float* weight_n = (const float*)d_in[4];
    float* out = (float*)d_out;
    char* ws = (char*)d_ws;

    const size_t o_xnb  = 0;
    const size_t o_wb   = o_xnb + (size_t)BATCH * DIM * 2;
    const size_t o_wqb  = o_wb  + (size_t)NPAD * DIM * 2;
    const size_t o_wkb  = o_wqb + (size_t)BATCH * DIM * 2;
    const size_t o_sim  = o_wkb + (size_t)BATCH * DIM * 2;
    const size_t o_misc = o_sim + (size_t)BATCH * BATCH * 4;

    u16* xnb = (u16*)(ws + o_xnb);
    u16* wb  = (u16*)(ws + o_wb);
    u16* wqb = (u16*)(ws + o_wqb);
    u16* wkb = (u16*)(ws + o_wkb);
    float* sim = (float*)(ws + o_sim);
    float* mf  = (float*)(ws + o_misc);

    // zeroed by norm_all (33*256 = 8448 floats)
    float* sumexp   = mf;               // 2048
    float* sumlogit = mf + 2048;        // 2048
    float* msum     = mf + 4096;        // 2048
    float* mcnt     = mf + 6144;        // 2048
    float* zn       = mf + 8192;        // 1
    float* zneg     = mf + 8193;        // 1 (plain store, needs no zeroing)
    // non-zeroed (fully overwritten every launch)
    float* philab  = mf + 8448;         // 2048
    float* ap      = mf + 10496;        // 2048

    norm_all_kernel<<<BATCH + NPAD + BATCH, 256, 0, stream>>>(
        x, weight, weight_m, weight_n, label,
        (u32*)xnb, (u32*)wb, (u32*)wqb, (u32*)wkb, mf);

    dim3 g_aam(BATCH / 128, NPAD / 128);   // (16, 79)
    gemm_aam_kernel<<<g_aam, 256, 0, stream>>>(xnb, wb, label, sumexp, sumlogit, philab);

    dim3 g_cc(BATCH / 128, BATCH / 64);    // (16, 32)
    gemm_cc_kernel<<<g_cc, 256, 0, stream>>>(xnb, wqb, wkb, label, sim, msum, mcnt, ap);

    cc_pass2_kernel<<<256, 256, 0, stream>>>(sim, label, msum, mcnt, ap, zn, zneg);

    finalize_kernel<<<1, 256, 0, stream>>>(sumexp, sumlogit, philab, zn, zneg, out);
}

// Round 5
// 191.692 us; speedup vs baseline: 1.3549x; 1.0386x over previous
//
#include <hip/hip_runtime.h>
#include <hip/hip_bf16.h>

typedef unsigned short u16;
typedef unsigned int u32;
typedef __bf16 v8bf __attribute__((ext_vector_type(8)));
typedef float f32x4 __attribute__((ext_vector_type(4)));
typedef unsigned int u32x4 __attribute__((ext_vector_type(4)));

constexpr int BATCH = 2048;
constexpr int DIM   = 512;
constexpr int NCLS  = 10000;
constexpr int NPAD  = 10240;   // 80 * 128 (zero-padded rows; enables clean XCD swizzle)

#define F_S     30.0f
#define F_COS_M 0.9800665778412416f
#define F_SIN_M 0.19866933079506122f
#define F_TH   (-0.9800665778412416f)
#define F_MM    0.03973386615901224f

#define G_AAM  1280   // 16 bm x 80 bn
#define G_CC    512   // 16 bm x 32 bn

static __device__ __forceinline__ float clampf(float v, float lo, float hi) {
    return fminf(fmaxf(v, lo), hi);
}
static __device__ __forceinline__ u16 f2bf(float v) {
    __hip_bfloat16 h = __float2bfloat16(v);
    return __builtin_bit_cast(unsigned short, h);
}
// async global->LDS, 16B per lane. LDS dest is wave-uniform base + lane*16 (source may scatter).
static __device__ __forceinline__ void glds16(const void* g, void* l) {
    __builtin_amdgcn_global_load_lds(
        (const __attribute__((address_space(1))) unsigned int*)g,
        (__attribute__((address_space(3))) unsigned int*)l, 16, 0, 0);
}
static __device__ __forceinline__ float blk_sum(float v, float* sh, int t) {
#pragma unroll
    for (int o = 32; o > 0; o >>= 1) v += __shfl_down(v, o, 64);
    __syncthreads();
    if ((t & 63) == 0) sh[t >> 6] = v;
    __syncthreads();
    return sh[0] + sh[1] + sh[2] + sh[3];
}

// ============ merged normalize (x | w | gathered wm/wn) + acc zeroing ============
__global__ __launch_bounds__(256) void norm_all_kernel(const float* __restrict__ x,
                                                       const float* __restrict__ w,
                                                       const float* __restrict__ wm,
                                                       const float* __restrict__ wn,
                                                       const int* __restrict__ label,
                                                       u32* __restrict__ xnb,
                                                       u32* __restrict__ wb,
                                                       u32* __restrict__ wqb,
                                                       u32* __restrict__ wkb,
                                                       float* __restrict__ zacc) {
    __shared__ float sh[8];
    const int b = blockIdx.x, t = threadIdx.x;
    if (b < 33) zacc[b * 256 + t] = 0.f;   // zero accumulators (8448 >= 8193 used)

    if (b < BATCH) {
        const float2 v = ((const float2*)(x + (size_t)b * DIM))[t];
        float s = blk_sum(v.x * v.x + v.y * v.y, sh, t);
        float inv = 1.0f / fmaxf(sqrtf(s), 1e-12f);
        xnb[(size_t)b * 256 + t] = (u32)f2bf(v.x * inv) | ((u32)f2bf(v.y * inv) << 16);
    } else if (b < BATCH + NPAD) {
        const int row = b - BATCH;
        if (row >= NCLS) {  // uniform per block
            wb[(size_t)row * 256 + t] = 0;
            return;
        }
        const float2 v = ((const float2*)(w + (size_t)row * DIM))[t];
        float s = blk_sum(v.x * v.x + v.y * v.y, sh, t);
        float inv = 1.0f / fmaxf(sqrtf(s), 1e-12f);
        wb[(size_t)row * 256 + t] = (u32)f2bf(v.x * inv) | ((u32)f2bf(v.y * inv) << 16);
    } else {
        const int i = b - (BATCH + NPAD);
        const int g = label[i];
        const float2 q = ((const float2*)(wm + (size_t)g * DIM))[t];
        const float2 k = ((const float2*)(wn + (size_t)g * DIM))[t];
        float sq = blk_sum(q.x * q.x + q.y * q.y, sh, t);
        float sk = blk_sum(k.x * k.x + k.y * k.y, sh + 4, t);
        float iq = 1.0f / fmaxf(sqrtf(sq), 1e-12f);
        float ik = 1.0f / fmaxf(sqrtf(sk), 1e-12f);
        wqb[(size_t)i * 256 + t] = (u32)f2bf(q.x * iq) | ((u32)f2bf(q.y * iq) << 16);
        wkb[(size_t)i * 256 + t] = (u32)f2bf(k.x * ik) | ((u32)f2bf(k.y * ik) << 16);
    }
}

// ============ FUSED GEMM dispatch: blocks [0,1280) = AAM, [1280,1792) = CC ============
// Both roles: 33 KB LDS (union), XOR-swizzled conflict-free layout, XCD-aware bn mapping
// (xcd = flat&7 owns a contiguous set of bn columns -> per-XCD L2 working set < 4 MB).
__global__ __launch_bounds__(256) void gemm_fused_kernel(const u16* __restrict__ A,
                                                         const u16* __restrict__ Bw,
                                                         const u16* __restrict__ Bq,
                                                         const u16* __restrict__ Bk,
                                                         const int* __restrict__ label,
                                                         float* __restrict__ sumexp,
                                                         float* __restrict__ sumlogit,
                                                         float* __restrict__ philab,
                                                         float* __restrict__ sim,
                                                         float* __restrict__ msum,
                                                         float* __restrict__ mcnt,
                                                         float* __restrict__ ap) {
    __shared__ __align__(16) u16 sA[128 * 64];   // 16 KB
    __shared__ __align__(16) u16 sB[128 * 64];   // 16 KB (CC: Qs = sB[0:4096], Ks = sB[4096:8192])
    __shared__ float red0[128];
    __shared__ float red1[128];

    const int t = threadIdx.x;
    const int lane = t & 63, wave = t >> 6;
    const int fr = lane & 15, quad = lane >> 4;
    const int swz = fr & 7;

    if (t < 128) { red0[t] = 0.f; red1[t] = 0.f; }

    const int srow = t >> 3;                 // 0..31
    const int scg  = (t & 7) ^ (srow & 7);   // swizzled global chunk (row+32k keeps same swz: 32%8==0)

    if (blockIdx.x < G_AAM) {
        // ---------------- AAM role: 128x128 tile, BK=64 ----------------
        const int flat = blockIdx.x;
        const int xcd = flat & 7, r = flat >> 3;
        const int bm = r & 15;
        const int bn = (r >> 4) * 8 + xcd;   // 10 bn per xcd -> 1.28 MB B + 2 MB A per XCD L2

        const int wm = (wave >> 1) * 64, wn = (wave & 1) * 64;
        const u16* ag = A  + (size_t)(bm * 128 + srow) * DIM + scg * 8;
        const u16* bg = Bw + (size_t)(bn * 128 + srow) * DIM + scg * 8;
        u16* al = &sA[t * 8];
        u16* bl = &sB[t * 8];

        f32x4 acc[4][4] = {};

        for (int k0 = 0; k0 < DIM; k0 += 64) {
#pragma unroll
            for (int r2 = 0; r2 < 4; r2++) {
                glds16(ag + (size_t)(r2 * 32) * DIM + k0, al + r2 * 2048);
                glds16(bg + (size_t)(r2 * 32) * DIM + k0, bl + r2 * 2048);
            }
            __syncthreads();
#pragma unroll
            for (int ks = 0; ks < 2; ks++) {
                const int slot = ((ks << 2) | quad) ^ swz;
                v8bf af[4], bf[4];
#pragma unroll
                for (int f = 0; f < 4; f++) {
                    af[f] = __builtin_bit_cast(v8bf, *(const u32x4*)&sA[(wm + f * 16 + fr) * 64 + slot * 8]);
                    bf[f] = __builtin_bit_cast(v8bf, *(const u32x4*)&sB[(wn + f * 16 + fr) * 64 + slot * 8]);
                }
#pragma unroll
                for (int i = 0; i < 4; i++)
#pragma unroll
                    for (int j = 0; j < 4; j++)
                        acc[i][j] = __builtin_amdgcn_mfma_f32_16x16x32_bf16(af[i], bf[j], acc[i][j], 0, 0, 0);
            }
            __syncthreads();
        }

        // Epilogue: per-row partial Σexp(logit), Σlogit (logits<=30 -> fp32 safe, no max-sub)
#pragma unroll
        for (int i = 0; i < 4; i++) {
#pragma unroll
            for (int r3 = 0; r3 < 4; r3++) {
                const int ml = wm + i * 16 + quad * 4 + r3;
                const int mg = bm * 128 + ml;
                const int lab = label[mg];
                float esum = 0.f, lsum = 0.f;
#pragma unroll
                for (int j = 0; j < 4; j++) {
                    const int ng = bn * 128 + wn + j * 16 + fr;
                    if (ng < NCLS) {
                        float c = acc[i][j][r3];
                        float logit;
                        if (ng == lab) {
                            float sine = sqrtf(clampf(1.f - c * c, 0.f, 1.f));
                            float phi = c * F_COS_M - sine * F_SIN_M;
                            float val = ((c - F_TH) > 0.f) ? phi : (c - F_MM);
                            logit = F_S * val;
                            philab[mg] = logit;
                        } else {
                            logit = F_S * c;
                        }
                        esum += __expf(logit);
                        lsum += logit;
                    }
                }
#pragma unroll
                for (int off = 1; off < 16; off <<= 1) {
                    esum += __shfl_xor(esum, off, 64);
                    lsum += __shfl_xor(lsum, off, 64);
                }
                if (fr == 0) {
                    atomicAdd(&red0[ml], esum);
                    atomicAdd(&red1[ml], lsum);
                }
            }
        }
        __syncthreads();
        if (t < 128) {
            atomicAdd(&sumexp[bm * 128 + t], red0[t]);
            atomicAdd(&sumlogit[bm * 128 + t], red1[t]);
        }
    } else {
        // ---------------- CC role: dual GEMM, 128x64 tile, BK=64 ----------------
        const int c = blockIdx.x - G_AAM;
        const int xcd = c & 7, r = c >> 3;
        const int bm = r & 15;
        const int bn = (r >> 4) * 8 + xcd;   // 4 bn per xcd -> 0.5 MB Q/K + 2 MB A per XCD L2

        const int wm = (wave >> 1) * 64, wn = (wave & 1) * 32;
        u16* Qs = sB;
        u16* Ks = sB + 64 * 64;

        const u16* ag = A  + (size_t)(bm * 128 + srow) * DIM + scg * 8;
        const u16* qg = Bq + (size_t)(bn * 64 + srow) * DIM + scg * 8;
        const u16* kg = Bk + (size_t)(bn * 64 + srow) * DIM + scg * 8;
        u16* al = &sA[t * 8];
        u16* ql = &Qs[t * 8];
        u16* kl = &Ks[t * 8];

        f32x4 aq[4][2] = {};
        f32x4 ak[4][2] = {};

        for (int k0 = 0; k0 < DIM; k0 += 64) {
#pragma unroll
            for (int r2 = 0; r2 < 4; r2++)
                glds16(ag + (size_t)(r2 * 32) * DIM + k0, al + r2 * 2048);
#pragma unroll
            for (int r2 = 0; r2 < 2; r2++) {
                glds16(qg + (size_t)(r2 * 32) * DIM + k0, ql + r2 * 2048);
                glds16(kg + (size_t)(r2 * 32) * DIM + k0, kl + r2 * 2048);
            }
            __syncthreads();
#pragma unroll
            for (int ks = 0; ks < 2; ks++) {
                const int slot = ((ks << 2) | quad) ^ swz;
                v8bf af[4], qf[2], kf[2];
#pragma unroll
                for (int f = 0; f < 4; f++)
                    af[f] = __builtin_bit_cast(v8bf, *(const u32x4*)&sA[(wm + f * 16 + fr) * 64 + slot * 8]);
#pragma unroll
                for (int f = 0; f < 2; f++) {
                    qf[f] = __builtin_bit_cast(v8bf, *(const u32x4*)&Qs[(wn + f * 16 + fr) * 64 + slot * 8]);
                    kf[f] = __builtin_bit_cast(v8bf, *(const u32x4*)&Ks[(wn + f * 16 + fr) * 64 + slot * 8]);
                }
#pragma unroll
                for (int i = 0; i < 4; i++)
#pragma unroll
                    for (int j = 0; j < 2; j++) {
                        aq[i][j] = __builtin_amdgcn_mfma_f32_16x16x32_bf16(af[i], qf[j], aq[i][j], 0, 0, 0);
                        ak[i][j] = __builtin_amdgcn_mfma_f32_16x16x32_bf16(af[i], kf[j], ak[i][j], 0, 0, 0);
                    }
            }
            __syncthreads();
        }

        int lab_n[2];
#pragma unroll
        for (int j = 0; j < 2; j++) lab_n[j] = label[bn * 64 + wn + j * 16 + fr];

#pragma unroll
        for (int i = 0; i < 4; i++) {
#pragma unroll
            for (int r3 = 0; r3 < 4; r3++) {
                const int ml = wm + i * 16 + quad * 4 + r3;
                const int mg = bm * 128 + ml;
                const int lm = label[mg];
                float ms = 0.f, mc = 0.f;
#pragma unroll
                for (int j = 0; j < 2; j++) {
                    const int ng = bn * 64 + wn + j * 16 + fr;
                    float s = aq[i][j][r3] * ak[i][j][r3];
                    sim[(size_t)mg * BATCH + ng] = s;
                    if (lab_n[j] == lm) { ms += s; mc += 1.f; }
                    if (mg == ng) ap[mg] = s;   // unique writer; read next dispatch
                }
#pragma unroll
                for (int off = 1; off < 16; off <<= 1) {
                    ms += __shfl_xor(ms, off, 64);
                    mc += __shfl_xor(mc, off, 64);
                }
                if (fr == 0) {
                    atomicAdd(&red0[ml], ms);
                    atomicAdd(&red1[ml], mc);
                }
            }
        }
        __syncthreads();
        if (t < 128) {
            atomicAdd(&msum[bm * 128 + t], red0[t]);
            atomicAdd(&mcnt[bm * 128 + t], red1[t]);
        }
    }
}

// ============ CC pass 2: masked Σexp(phi_nm); apm recomputed into LDS per block ============
__global__ __launch_bounds__(256) void cc_pass2_kernel(const float* __restrict__ sim,
                                                       const int* __restrict__ label,
                                                       const float* __restrict__ msum,
                                                       const float* __restrict__ mcnt,
                                                       const float* __restrict__ ap,
                                                       float* __restrict__ zn,
                                                       float* __restrict__ zneg) {
    __shared__ __align__(16) float cam_s[BATCH];
    __shared__ __align__(16) float sam_s[BATCH];
    __shared__ float sh[4];
    const int t = threadIdx.x, b = blockIdx.x;

    for (int j = t; j < BATCH; j += 256) {
        float cam = clampf(msum[j] / mcnt[j], 0.f, 1.f);   // mcnt >= 1 (diagonal)
        cam_s[j] = cam;
        sam_s[j] = sqrtf(clampf(1.f - cam, 0.f, 1.f));
    }
    __syncthreads();

    float acc = 0.f;
#pragma unroll
    for (int row = 0; row < 8; row++) {
        const int i = b * 8 + row;
        const int li = label[i];
        const f32x4* simr = (const f32x4*)(sim + (size_t)i * BATCH);
        const f32x4* cap4 = (const f32x4*)cam_s;
        const f32x4* sap4 = (const f32x4*)sam_s;
#pragma unroll
        for (int k = 0; k < 2; k++) {
            const int jj = t + k * 256;
            f32x4 s4 = simr[jj];
            int4 l4i = ((const int4*)label)[jj];
            const int* l4 = (const int*)&l4i;
            f32x4 ca4 = cap4[jj];
            f32x4 sa4 = sap4[jj];
#pragma unroll
            for (int e = 0; e < 4; e++) {
                if (l4[e] != li) {
                    float can = clampf(s4[e], 0.f, 1.f);
                    float san = sqrtf(clampf(1.f - can, 0.f, 1.f));
                    float pns = san * ca4[e] + can * sa4[e];   // column-j broadcast
                    float pnc = sqrtf(clampf(1.f - pns, 0.f, 1.f));
                    acc += __expf(pns * F_COS_M - pnc * F_SIN_M);
                }
            }
        }
    }
    acc = blk_sum(acc, sh, t);
    if (t == 0) atomicAdd(zn, acc);

    if (b == 0) {   // logit_neg partition: Σexp(1 - phi_pm)
        float accN = 0.f;
        for (int i = t; i < BATCH; i += 256) {
            float cam = cam_s[i], sam = sam_s[i];
            float cap = clampf(ap[i], 0.f, 1.f);
            float sap = sqrtf(clampf(1.f - cap, 0.f, 1.f));
            float ppc = cap * cam - sap * sam;
            float pps = sqrtf(clampf(1.f - ppc, 0.f, 1.f));
            accN += __expf(1.f - (ppc * F_COS_M - pps * F_SIN_M));
        }
        accN = blk_sum(accN, sh, t);
        if (t == 0) zneg[0] = accN;
    }
}

// ============ finalize: single block ============
__global__ __launch_bounds__(256) void finalize_kernel(const float* __restrict__ sumexp,
                                                       const float* __restrict__ sumlogit,
                                                       const float* __restrict__ philab,
                                                       const float* __restrict__ zn,
                                                       const float* __restrict__ zneg,
                                                       float* __restrict__ out) {
    __shared__ float sh[4];
    const int t = threadIdx.x;
    float accA = 0.f;
    for (int r = t; r < BATCH; r += 256) {
        float lse = logf(sumexp[r]);
        accA += 0.9f * (philab[r] - lse) + 1e-5f * (sumlogit[r] - (float)NCLS * lse);
    }
    accA = blk_sum(accA, sh, t);
    if (t == 0) {
        float aam = -accA / (float)BATCH;
        float z = logf(zn[0]) + logf(zneg[0]);
        float cc = (z > 0.f) ? (z + log1pf(__expf(-z))) : log1pf(__expf(z));
        out[0] = aam + cc;
    }
}

extern "C" void kernel_launch(void* const* d_in, const int* in_sizes, int n_in,
                              void* d_out, int out_size, void* d_ws, size_t ws_size,
                              hipStream_t stream) {
    const float* x        = (const float*)d_in[0];
    const int*   label    = (const int*)d_in[1];
    const float* weight   = (const float*)d_in[2];
    const float* weight_m = (const float*)d_in[3];
    const float* weight_n = (const float*)d_in[4];
    float* out = (float*)d_out;
    char* ws = (char*)d_ws;

    const size_t o_xnb  = 0;
    const size_t o_wb   = o_xnb + (size_t)BATCH * DIM * 2;
    const size_t o_wqb  = o_wb  + (size_t)NPAD * DIM * 2;
    const size_t o_wkb  = o_wqb + (size_t)BATCH * DIM * 2;
    const size_t o_sim  = o_wkb + (size_t)BATCH * DIM * 2;
    const size_t o_misc = o_sim + (size_t)BATCH * BATCH * 4;

    u16* xnb = (u16*)(ws + o_xnb);
    u16* wb  = (u16*)(ws + o_wb);
    u16* wqb = (u16*)(ws + o_wqb);
    u16* wkb = (u16*)(ws + o_wkb);
    float* sim = (float*)(ws + o_sim);
    float* mf  = (float*)(ws + o_misc);

    // zeroed by norm_all (33*256 = 8448 floats)
    float* sumexp   = mf;               // 2048
    float* sumlogit = mf + 2048;        // 2048
    float* msum     = mf + 4096;        // 2048
    float* mcnt     = mf + 6144;        // 2048
    float* zn       = mf + 8192;        // 1
    float* zneg     = mf + 8193;        // 1 (plain store, needs no zeroing)
    // non-zeroed (fully overwritten every launch)
    float* philab  = mf + 8448;         // 2048
    float* ap      = mf + 10496;        // 2048

    norm_all_kernel<<<BATCH + NPAD + BATCH, 256, 0, stream>>>(
        x, weight, weight_m, weight_n, label,
        (u32*)xnb, (u32*)wb, (u32*)wqb, (u32*)wkb, mf);

    gemm_fused_kernel<<<G_AAM + G_CC, 256, 0, stream>>>(
        xnb, wb, wqb, wkb, label,
        sumexp, sumlogit, philab, sim, msum, mcnt, ap);

    cc_pass2_kernel<<<256, 256, 0, stream>>>(sim, label, msum, mcnt, ap, zn, zneg);

    finalize_kernel<<<1, 256, 0, stream>>>(sumexp, sumlogit, philab, zn, zneg, out);
}

// Round 6
// 187.273 us; speedup vs baseline: 1.3869x; 1.0236x over previous
//
#include <hip/hip_runtime.h>
#include <hip/hip_bf16.h>

typedef unsigned short u16;
typedef unsigned int u32;
typedef __bf16 v8bf __attribute__((ext_vector_type(8)));
typedef float f32x4 __attribute__((ext_vector_type(4)));
typedef unsigned int u32x4 __attribute__((ext_vector_type(4)));

constexpr int BATCH = 2048;
constexpr int DIM   = 512;
constexpr int NCLS  = 10000;
constexpr int NPAD  = 10240;   // 80 * 128 (zero-padded rows)

#define F_S     30.0f
#define F_COS_M 0.9800665778412416f
#define F_SIN_M 0.19866933079506122f
#define F_TH   (-0.9800665778412416f)
#define F_MM    0.03973386615901224f

#define G_AAM  1280   // 16 bm x 80 bn
#define G_CC    512   // 16 bm x 32 bn
#define LDR      72   // LDS row stride (u16): 144 B -> conflict-free b128 r/w (bank grp = (fr+quad)%8)

static __device__ __forceinline__ float clampf(float v, float lo, float hi) {
    return fminf(fmaxf(v, lo), hi);
}
static __device__ __forceinline__ u16 f2bf(float v) {
    __hip_bfloat16 h = __float2bfloat16(v);
    return __builtin_bit_cast(unsigned short, h);
}
// Barrier that drains ONLY LDS (lgkmcnt=0); global prefetch loads stay in flight.
// 0xc07f = vmcnt(63) expcnt(7) lgkmcnt(0) on gfx9-encoding.
static __device__ __forceinline__ void barrier_lds_only() {
    __builtin_amdgcn_s_waitcnt(0xc07f);
    __builtin_amdgcn_s_barrier();
}
static __device__ __forceinline__ void barrier_raw() {
    __builtin_amdgcn_s_barrier();
}
static __device__ __forceinline__ float blk_sum(float v, float* sh, int t) {
#pragma unroll
    for (int o = 32; o > 0; o >>= 1) v += __shfl_down(v, o, 64);
    __syncthreads();
    if ((t & 63) == 0) sh[t >> 6] = v;
    __syncthreads();
    return sh[0] + sh[1] + sh[2] + sh[3];
}

// ============ normalize: one WAVE per row, no barriers ============
// rows: [0,2048)=x  [2048,12288)=w  [12288,14336)=wm[label]  [14336,16384)=wn[label]
__global__ __launch_bounds__(256) void norm_all_kernel(const float* __restrict__ x,
                                                       const float* __restrict__ w,
                                                       const float* __restrict__ wm,
                                                       const float* __restrict__ wn,
                                                       const int* __restrict__ label,
                                                       u32* __restrict__ xnb,
                                                       u32* __restrict__ wb,
                                                       u32* __restrict__ wqb,
                                                       u32* __restrict__ wkb,
                                                       float* __restrict__ zacc) {
    const int t = threadIdx.x, lane = t & 63, wv = t >> 6;
    const int b = blockIdx.x;
    if (b < 33) zacc[b * 256 + t] = 0.f;   // zero accumulators (8448 >= 8193 used)

    const int row = b * 4 + wv;
    const float* src;
    u32* dst;
    if (row < BATCH) {
        src = x + (size_t)row * DIM;
        dst = xnb + (size_t)row * 256;
    } else if (row < BATCH + NPAD) {
        const int r = row - BATCH;
        dst = wb + (size_t)r * 256;
        if (r >= NCLS) {   // zero pad rows (wave-uniform)
            u32x4 z = {0, 0, 0, 0};
            ((u32x4*)dst)[lane] = z;
            return;
        }
        src = w + (size_t)r * DIM;
    } else if (row < BATCH + NPAD + BATCH) {
        const int i = row - (BATCH + NPAD);
        src = wm + (size_t)label[i] * DIM;
        dst = wqb + (size_t)i * 256;
    } else {
        const int i = row - (BATCH + NPAD + BATCH);
        src = wn + (size_t)label[i] * DIM;
        dst = wkb + (size_t)i * 256;
    }
    const float4 v0 = ((const float4*)src)[lane * 2];
    const float4 v1 = ((const float4*)src)[lane * 2 + 1];
    float s = v0.x * v0.x + v0.y * v0.y + v0.z * v0.z + v0.w * v0.w
            + v1.x * v1.x + v1.y * v1.y + v1.z * v1.z + v1.w * v1.w;
#pragma unroll
    for (int o = 32; o > 0; o >>= 1) s += __shfl_xor(s, o, 64);
    const float inv = 1.0f / fmaxf(sqrtf(s), 1e-12f);
    u32x4 o4;
    o4[0] = (u32)f2bf(v0.x * inv) | ((u32)f2bf(v0.y * inv) << 16);
    o4[1] = (u32)f2bf(v0.z * inv) | ((u32)f2bf(v0.w * inv) << 16);
    o4[2] = (u32)f2bf(v1.x * inv) | ((u32)f2bf(v1.y * inv) << 16);
    o4[3] = (u32)f2bf(v1.z * inv) | ((u32)f2bf(v1.w * inv) << 16);
    ((u32x4*)dst)[lane] = o4;
}

// ============ FUSED GEMM: [0,1280)=AAM, [1280,1792)=CC ============
// Pipelined K-loop: register prefetch of tile k+1 issued before barrier; raw s_barrier with
// lgkmcnt-only drain keeps global loads in flight across the MFMA section (AITER-style).
// LDS stride 72 u16: conflict-free ds_write_b128/ds_read_b128, no swizzle needed.
__global__ __launch_bounds__(256) void gemm_fused_kernel(const u16* __restrict__ A,
                                                         const u16* __restrict__ Bw,
                                                         const u16* __restrict__ Bq,
                                                         const u16* __restrict__ Bk,
                                                         const int* __restrict__ label,
                                                         float* __restrict__ sumexp,
                                                         float* __restrict__ sumlogit,
                                                         float* __restrict__ philab,
                                                         float* __restrict__ sim,
                                                         float* __restrict__ msum,
                                                         float* __restrict__ mcnt,
                                                         float* __restrict__ ap) {
    __shared__ __align__(16) u16 sA[128 * LDR];   // 18 KB
    __shared__ __align__(16) u16 sB[128 * LDR];   // 18 KB (CC: Qs=[0,64*LDR), Ks=[64*LDR,...))
    __shared__ float red0[128];
    __shared__ float red1[128];

    const int t = threadIdx.x;
    const int lane = t & 63, wave = t >> 6;
    const int fr = lane & 15, quad = lane >> 4;

    if (t < 128) { red0[t] = 0.f; red1[t] = 0.f; }

    const int srow = t >> 3;   // 0..31
    const int sch  = t & 7;    // 16B chunk
    const int lw   = srow * LDR + sch * 8;

    if (blockIdx.x < G_AAM) {
        // ---------------- AAM role: 128x128 tile, BK=64 ----------------
        const int flat = blockIdx.x;
        const int xcd = flat & 7, r = flat >> 3;
        const int bm = r & 15;
        const int bn = (r >> 4) * 8 + xcd;   // per-XCD L2 working set < 4 MB

        const int wm = (wave >> 1) * 64, wn = (wave & 1) * 64;
        const u16* ag = A  + (size_t)(bm * 128 + srow) * DIM + sch * 8;
        const u16* bg = Bw + (size_t)(bn * 128 + srow) * DIM + sch * 8;

        u32x4 pa[4], pb[4];
#pragma unroll
        for (int r2 = 0; r2 < 4; r2++) {
            pa[r2] = *(const u32x4*)(ag + (size_t)(r2 * 32) * DIM);
            pb[r2] = *(const u32x4*)(bg + (size_t)(r2 * 32) * DIM);
        }

        f32x4 acc[4][4] = {};

#pragma unroll
        for (int k0 = 0; k0 < DIM; k0 += 64) {
#pragma unroll
            for (int r2 = 0; r2 < 4; r2++) {
                *(u32x4*)&sA[lw + r2 * 32 * LDR] = pa[r2];
                *(u32x4*)&sB[lw + r2 * 32 * LDR] = pb[r2];
            }
            if (k0 + 64 < DIM) {   // prefetch next tile; stays in flight across barriers
#pragma unroll
                for (int r2 = 0; r2 < 4; r2++) {
                    pa[r2] = *(const u32x4*)(ag + (size_t)(r2 * 32) * DIM + k0 + 64);
                    pb[r2] = *(const u32x4*)(bg + (size_t)(r2 * 32) * DIM + k0 + 64);
                }
            }
            barrier_lds_only();
#pragma unroll
            for (int ks = 0; ks < 2; ks++) {
                v8bf af[4], bf[4];
#pragma unroll
                for (int f = 0; f < 4; f++) {
                    af[f] = __builtin_bit_cast(v8bf, *(const u32x4*)&sA[(wm + f * 16 + fr) * LDR + ks * 32 + quad * 8]);
                    bf[f] = __builtin_bit_cast(v8bf, *(const u32x4*)&sB[(wn + f * 16 + fr) * LDR + ks * 32 + quad * 8]);
                }
#pragma unroll
                for (int i = 0; i < 4; i++)
#pragma unroll
                    for (int j = 0; j < 4; j++)
                        acc[i][j] = __builtin_amdgcn_mfma_f32_16x16x32_bf16(af[i], bf[j], acc[i][j], 0, 0, 0);
            }
            barrier_raw();
        }

        // Epilogue: per-row partial Σexp(logit), Σlogit (logits<=30 -> fp32 safe, no max-sub)
#pragma unroll
        for (int i = 0; i < 4; i++) {
#pragma unroll
            for (int r3 = 0; r3 < 4; r3++) {
                const int ml = wm + i * 16 + quad * 4 + r3;
                const int mg = bm * 128 + ml;
                const int lab = label[mg];
                float esum = 0.f, lsum = 0.f;
#pragma unroll
                for (int j = 0; j < 4; j++) {
                    const int ng = bn * 128 + wn + j * 16 + fr;
                    if (ng < NCLS) {
                        float c = acc[i][j][r3];
                        float logit;
                        if (ng == lab) {
                            float sine = sqrtf(clampf(1.f - c * c, 0.f, 1.f));
                            float phi = c * F_COS_M - sine * F_SIN_M;
                            float val = ((c - F_TH) > 0.f) ? phi : (c - F_MM);
                            logit = F_S * val;
                            philab[mg] = logit;
                        } else {
                            logit = F_S * c;
                        }
                        esum += __expf(logit);
                        lsum += logit;
                    }
                }
#pragma unroll
                for (int off = 1; off < 16; off <<= 1) {
                    esum += __shfl_xor(esum, off, 64);
                    lsum += __shfl_xor(lsum, off, 64);
                }
                if (fr == 0) {
                    atomicAdd(&red0[ml], esum);
                    atomicAdd(&red1[ml], lsum);
                }
            }
        }
        __syncthreads();
        if (t < 128) {
            atomicAdd(&sumexp[bm * 128 + t], red0[t]);
            atomicAdd(&sumlogit[bm * 128 + t], red1[t]);
        }
    } else {
        // ---------------- CC role: dual GEMM, 128x64 tile, BK=64 ----------------
        const int c = blockIdx.x - G_AAM;
        const int xcd = c & 7, r = c >> 3;
        const int bm = r & 15;
        const int bn = (r >> 4) * 8 + xcd;

        const int wm = (wave >> 1) * 64, wn = (wave & 1) * 32;
        u16* Qs = sB;
        u16* Ks = sB + 64 * LDR;

        const u16* ag = A  + (size_t)(bm * 128 + srow) * DIM + sch * 8;
        const u16* qg = Bq + (size_t)(bn * 64 + srow) * DIM + sch * 8;
        const u16* kg = Bk + (size_t)(bn * 64 + srow) * DIM + sch * 8;

        u32x4 pa[4], pq[2], pk[2];
#pragma unroll
        for (int r2 = 0; r2 < 4; r2++)
            pa[r2] = *(const u32x4*)(ag + (size_t)(r2 * 32) * DIM);
#pragma unroll
        for (int r2 = 0; r2 < 2; r2++) {
            pq[r2] = *(const u32x4*)(qg + (size_t)(r2 * 32) * DIM);
            pk[r2] = *(const u32x4*)(kg + (size_t)(r2 * 32) * DIM);
        }

        f32x4 aq[4][2] = {};
        f32x4 ak[4][2] = {};

#pragma unroll
        for (int k0 = 0; k0 < DIM; k0 += 64) {
#pragma unroll
            for (int r2 = 0; r2 < 4; r2++)
                *(u32x4*)&sA[lw + r2 * 32 * LDR] = pa[r2];
#pragma unroll
            for (int r2 = 0; r2 < 2; r2++) {
                *(u32x4*)&Qs[lw + r2 * 32 * LDR] = pq[r2];
                *(u32x4*)&Ks[lw + r2 * 32 * LDR] = pk[r2];
            }
            if (k0 + 64 < DIM) {
#pragma unroll
                for (int r2 = 0; r2 < 4; r2++)
                    pa[r2] = *(const u32x4*)(ag + (size_t)(r2 * 32) * DIM + k0 + 64);
#pragma unroll
                for (int r2 = 0; r2 < 2; r2++) {
                    pq[r2] = *(const u32x4*)(qg + (size_t)(r2 * 32) * DIM + k0 + 64);
                    pk[r2] = *(const u32x4*)(kg + (size_t)(r2 * 32) * DIM + k0 + 64);
                }
            }
            barrier_lds_only();
#pragma unroll
            for (int ks = 0; ks < 2; ks++) {
                v8bf af[4], qf[2], kf[2];
#pragma unroll
                for (int f = 0; f < 4; f++)
                    af[f] = __builtin_bit_cast(v8bf, *(const u32x4*)&sA[(wm + f * 16 + fr) * LDR + ks * 32 + quad * 8]);
#pragma unroll
                for (int f = 0; f < 2; f++) {
                    qf[f] = __builtin_bit_cast(v8bf, *(const u32x4*)&Qs[(wn + f * 16 + fr) * LDR + ks * 32 + quad * 8]);
                    kf[f] = __builtin_bit_cast(v8bf, *(const u32x4*)&Ks[(wn + f * 16 + fr) * LDR + ks * 32 + quad * 8]);
                }
#pragma unroll
                for (int i = 0; i < 4; i++)
#pragma unroll
                    for (int j = 0; j < 2; j++) {
                        aq[i][j] = __builtin_amdgcn_mfma_f32_16x16x32_bf16(af[i], qf[j], aq[i][j], 0, 0, 0);
                        ak[i][j] = __builtin_amdgcn_mfma_f32_16x16x32_bf16(af[i], kf[j], ak[i][j], 0, 0, 0);
                    }
            }
            barrier_raw();
        }

        int lab_n[2];
#pragma unroll
        for (int j = 0; j < 2; j++) lab_n[j] = label[bn * 64 + wn + j * 16 + fr];

#pragma unroll
        for (int i = 0; i < 4; i++) {
#pragma unroll
            for (int r3 = 0; r3 < 4; r3++) {
                const int ml = wm + i * 16 + quad * 4 + r3;
                const int mg = bm * 128 + ml;
                const int lm = label[mg];
                float ms = 0.f, mc = 0.f;
#pragma unroll
                for (int j = 0; j < 2; j++) {
                    const int ng = bn * 64 + wn + j * 16 + fr;
                    float s = aq[i][j][r3] * ak[i][j][r3];
                    sim[(size_t)mg * BATCH + ng] = s;
                    if (lab_n[j] == lm) { ms += s; mc += 1.f; }
                    if (mg == ng) ap[mg] = s;   // unique writer; read next dispatch
                }
#pragma unroll
                for (int off = 1; off < 16; off <<= 1) {
                    ms += __shfl_xor(ms, off, 64);
                    mc += __shfl_xor(mc, off, 64);
                }
                if (fr == 0) {
                    atomicAdd(&red0[ml], ms);
                    atomicAdd(&red1[ml], mc);
                }
            }
        }
        __syncthreads();
        if (t < 128) {
            atomicAdd(&msum[bm * 128 + t], red0[t]);
            atomicAdd(&mcnt[bm * 128 + t], red1[t]);
        }
    }
}

// ============ CC pass 2: masked Σexp(phi_nm); 512 blocks x 4 rows ============
__global__ __launch_bounds__(256) void cc_pass2_kernel(const float* __restrict__ sim,
                                                       const int* __restrict__ label,
                                                       const float* __restrict__ msum,
                                                       const float* __restrict__ mcnt,
                                                       const float* __restrict__ ap,
                                                       float* __restrict__ zn,
                                                       float* __restrict__ zneg) {
    __shared__ __align__(16) float cam_s[BATCH];
    __shared__ __align__(16) float sam_s[BATCH];
    __shared__ float sh[4];
    const int t = threadIdx.x, b = blockIdx.x;

    for (int j = t; j < BATCH; j += 256) {
        float cam = clampf(msum[j] / mcnt[j], 0.f, 1.f);   // mcnt >= 1 (diagonal)
        cam_s[j] = cam;
        sam_s[j] = sqrtf(clampf(1.f - cam, 0.f, 1.f));
    }
    __syncthreads();

    float acc = 0.f;
#pragma unroll
    for (int row = 0; row < 4; row++) {
        const int i = b * 4 + row;
        const int li = label[i];
        const f32x4* simr = (const f32x4*)(sim + (size_t)i * BATCH);
        const f32x4* cap4 = (const f32x4*)cam_s;
        const f32x4* sap4 = (const f32x4*)sam_s;
#pragma unroll
        for (int k = 0; k < 2; k++) {
            const int jj = t + k * 256;
            f32x4 s4 = simr[jj];
            int4 l4i = ((const int4*)label)[jj];
            const int* l4 = (const int*)&l4i;
            f32x4 ca4 = cap4[jj];
            f32x4 sa4 = sap4[jj];
#pragma unroll
            for (int e = 0; e < 4; e++) {
                if (l4[e] != li) {
                    float can = clampf(s4[e], 0.f, 1.f);
                    float san = sqrtf(clampf(1.f - can, 0.f, 1.f));
                    float pns = san * ca4[e] + can * sa4[e];   // column-j broadcast
                    float pnc = sqrtf(clampf(1.f - pns, 0.f, 1.f));
                    acc += __expf(pns * F_COS_M - pnc * F_SIN_M);
                }
            }
        }
    }
    acc = blk_sum(acc, sh, t);
    if (t == 0) atomicAdd(zn, acc);

    if (b == 0) {   // logit_neg partition: Σexp(1 - phi_pm)
        float accN = 0.f;
        for (int i = t; i < BATCH; i += 256) {
            float cam = cam_s[i], sam = sam_s[i];
            float cap = clampf(ap[i], 0.f, 1.f);
            float sap = sqrtf(clampf(1.f - cap, 0.f, 1.f));
            float ppc = cap * cam - sap * sam;
            float pps = sqrtf(clampf(1.f - ppc, 0.f, 1.f));
            accN += __expf(1.f - (ppc * F_COS_M - pps * F_SIN_M));
        }
        accN = blk_sum(accN, sh, t);
        if (t == 0) zneg[0] = accN;
    }
}

// ============ finalize: single block ============
__global__ __launch_bounds__(256) void finalize_kernel(const float* __restrict__ sumexp,
                                                       const float* __restrict__ sumlogit,
                                                       const float* __restrict__ philab,
                                                       const float* __restrict__ zn,
                                                       const float* __restrict__ zneg,
                                                       float* __restrict__ out) {
    __shared__ float sh[4];
    const int t = threadIdx.x;
    float accA = 0.f;
    for (int r = t; r < BATCH; r += 256) {
        float lse = logf(sumexp[r]);
        accA += 0.9f * (philab[r] - lse) + 1e-5f * (sumlogit[r] - (float)NCLS * lse);
    }
    accA = blk_sum(accA, sh, t);
    if (t == 0) {
        float aam = -accA / (float)BATCH;
        float z = logf(zn[0]) + logf(zneg[0]);
        float cc = (z > 0.f) ? (z + log1pf(__expf(-z))) : log1pf(__expf(z));
        out[0] = aam + cc;
    }
}

extern "C" void kernel_launch(void* const* d_in, const int* in_sizes, int n_in,
                              void* d_out, int out_size, void* d_ws, size_t ws_size,
                              hipStream_t stream) {
    const float* x        = (const float*)d_in[0];
    const int*   label    = (const int*)d_in[1];
    const float* weight   = (const float*)d_in[2];
    const float* weight_m = (const float*)d_in[3];
    const float* weight_n = (const float*)d_in[4];
    float* out = (float*)d_out;
    char* ws = (char*)d_ws;

    const size_t o_xnb  = 0;
    const size_t o_wb   = o_xnb + (size_t)BATCH * DIM * 2;
    const size_t o_wqb  = o_wb  + (size_t)NPAD * DIM * 2;
    const size_t o_wkb  = o_wqb + (size_t)BATCH * DIM * 2;
    const size_t o_sim  = o_wkb + (size_t)BATCH * DIM * 2;
    const size_t o_misc = o_sim + (size_t)BATCH * BATCH * 4;

    u16* xnb = (u16*)(ws + o_xnb);
    u16* wb  = (u16*)(ws + o_wb);
    u16* wqb = (u16*)(ws + o_wqb);
    u16* wkb = (u16*)(ws + o_wkb);
    float* sim = (float*)(ws + o_sim);
    float* mf  = (float*)(ws + o_misc);

    // zeroed by norm_all (33*256 = 8448 floats)
    float* sumexp   = mf;               // 2048
    float* sumlogit = mf + 2048;        // 2048
    float* msum     = mf + 4096;        // 2048
    float* mcnt     = mf + 6144;        // 2048
    float* zn       = mf + 8192;        // 1
    float* zneg     = mf + 8193;        // 1 (plain store, needs no zeroing)
    // non-zeroed (fully overwritten every launch)
    float* philab  = mf + 8448;         // 2048
    float* ap      = mf + 10496;        // 2048

    norm_all_kernel<<<(BATCH + NPAD + 2 * BATCH) / 4, 256, 0, stream>>>(
        x, weight, weight_m, weight_n, label,
        (u32*)xnb, (u32*)wb, (u32*)wqb, (u32*)wkb, mf);

    gemm_fused_kernel<<<G_AAM + G_CC, 256, 0, stream>>>(
        xnb, wb, wqb, wkb, label,
        sumexp, sumlogit, philab, sim, msum, mcnt, ap);

    cc_pass2_kernel<<<512, 256, 0, stream>>>(sim, label, msum, mcnt, ap, zn, zneg);

    finalize_kernel<<<1, 256, 0, stream>>>(sumexp, sumlogit, philab, zn, zneg, out);
}